// Round 11
// baseline (516.701 us; speedup 1.0000x reference)
//
#include <hip/hip_runtime.h>
#include <hip/hip_bf16.h>

#define NB 32
#define NN 1000
#define COMD 64
#define HIDD 256
#define KSEL 500
#define TI 16        // dst rows per k_gat block
#define NSPL 32      // n-splits for k_psum
#define ROWS 32      // ceil(NN/NSPL)
#define DSTRIDE 1024 // padded distT row stride

// k_prep role bases
#define PB_DT   0        // 256 dist-transpose tiles
#define PB_AQ1  256      // 1024 adjq comp   (32 j's per block)
#define PB_AQ2  1280     // 1024 adjq coop
#define PB_WP   2304     // 40 blocks x 4 rows = 160 Wp rows
#define PB_WCO  2344     // 24 blocks x 4 rows = 96 Wco rows
#define PB_MISC 2368     // flags, wd, bias dots
#define PB_N    2369

typedef __hip_bfloat16 bf16;
typedef unsigned long long u64;
typedef __attribute__((ext_vector_type(4))) float f32x4;
typedef __attribute__((ext_vector_type(8))) short s16x8;
typedef __attribute__((ext_vector_type(4))) short s16x4;
typedef __attribute__((ext_vector_type(4))) unsigned short u16x4;
typedef __attribute__((ext_vector_type(2))) unsigned long long u64x2;

__device__ __forceinline__ float b2f(bf16 x){ return __bfloat162float(x); }

template<bool F32>
__device__ __forceinline__ float ldf(const void* p, long i){
  return F32 ? ((const float*)p)[i] : b2f(((const bf16*)p)[i]);
}
template<bool BINT>
__device__ __forceinline__ bool ldb(const void* p, long i){
  return BINT ? (((const int*)p)[i] != 0) : (((const unsigned char*)p)[i] != 0);
}

__device__ __forceinline__ float wave_sum(float v){
#pragma unroll
  for (int o = 32; o > 0; o >>= 1) v += __shfl_down(v, o, 64);
  return v;
}
__device__ __forceinline__ float wave_bsum(float v){
#pragma unroll
  for (int o = 32; o > 0; o >>= 1) v += __shfl_xor(v, o, 64);
  return v;
}
__device__ __forceinline__ float wave_bmax(float v){
#pragma unroll
  for (int o = 32; o > 0; o >>= 1) v = fmaxf(v, __shfl_xor(v, o, 64));
  return v;
}
__device__ __forceinline__ int wave_bsum_i(int v){
#pragma unroll
  for (int o = 32; o > 0; o >>= 1) v += __shfl_xor(v, o, 64);
  return v;
}
__device__ __forceinline__ unsigned fkey(float f){
  unsigned u = __float_as_uint(f);
  return (u & 0x80000000u) ? ~u : (u | 0x80000000u);
}
// split fp32 into bf16 hi + bf16 lo with v ≈ hi + lo (residual ~2^-16 rel)
__device__ __forceinline__ void split_bf(float v, short& hi, short& lo){
  unsigned u = __float_as_uint(v);
  float hf = __uint_as_float(u & 0xFFFF0000u);
  hi = (short)(u >> 16);
  float r = v - hf;                 // exact
  lo = (short)(__float_as_uint(r) >> 16);
}
__device__ __forceinline__ short f2bs(float v){
  bf16 h = __float2bfloat16(v);
  short s; __builtin_memcpy(&s, &h, 2); return s;
}
__device__ __forceinline__ void hB_write(short* hB_hi, short* hB_lo,
                                         int b, int n, int ch, float v){
  int kb = n >> 5, g4 = (n >> 3) & 3, u = n & 7;
  long off = ((((long)b * 32 + kb) * 4 + g4) * 64 + ch) * 8 + u;
  short hi, lo; split_bf(v, hi, lo);
  hB_hi[off] = hi; hB_lo[off] = lo;
}
// cheap per-block dtype sniff: 2 loads + 2 ballots
__device__ __forceinline__ void sniff2(const void* dist, const void* adjc,
                                       int lane, int& f32, int& as_int){
  unsigned wdist = ((const unsigned*)dist)[lane];
  unsigned wadj  = ((const unsigned*)adjc)[lane];
  f32 = (__ballot((wdist & 0xFFFFu) >= 0x8000u) != 0ull) ? 1 : 0;
  as_int = (__ballot(wadj > 1u) == 0ull) ? 1 : 0;
}

// ================ k_prep: all input preprocessing in ONE kernel ================
template<bool F32>
__device__ void dist_t_role(const void* dist, bf16* distTb, int rel){
  __shared__ bf16 tile[64][68];
  int t = threadIdx.x;
  int wv = t >> 6, lane = t & 63;
  int it = (rel & 15) * 64, jt = (rel >> 4) * 64;
#pragma unroll
  for (int r = 0; r < 16; ++r){
    int jl = r * 4 + wv;
    int j = jt + jl, i = it + lane;
    float v = (j < NN && i < NN) ? ldf<F32>(dist, (long)j * NN + i) : 0.f;
    tile[jl][lane] = __float2bfloat16(v);
  }
  __syncthreads();
#pragma unroll
  for (int r = 0; r < 16; ++r){
    int il = r * 4 + wv;
    int i = it + il, j = jt + lane;
    if (i < NN) distTb[(long)i * DSTRIDE + j] = tile[lane][il];
  }
}
// adjacency pack v2: lane owns 16 consecutive i's, contiguous row reads
// (u64 loads for byte bools — row offsets are 8B-aligned since 1000%8==0;
//  dwordx4 for int bools — 16B-aligned since 4000%16==0), then 4 shuffles
// concatenate lane-quads into the u64 word for adjQ[b][iw][j].
template<bool BINT>
__device__ void adjq_role(const void* adj, u64* adjQ, int rel){
  int t = threadIdx.x;
  int wv = t >> 6, lane = t & 63;
  int j0 = (rel & 31) * 32;
  int b  = rel >> 5;
  int im = lane * 16;
  unsigned vmask = (im >= NN) ? 0u
                 : ((NN - im >= 16) ? 0xFFFFu : ((1u << (NN - im)) - 1u));
#pragma unroll
  for (int r = 0; r < 8; ++r){
    int j = j0 + wv * 8 + r;
    unsigned m = 0;
    if (j < NN){
      if (BINT){
        const char* p = (const char*)adj;
        long base = (((long)b * NN + j) * NN + im) * 4;
        long lim  = (long)NB * NN * NN * 4;
#pragma unroll
        for (int c = 0; c < 4; ++c){
          long off = base + c * 16;
          if (off + 16 <= lim){
            uint4 d = *(const uint4*)(p + off);
            m |= (d.x ? 1u : 0u) << (c * 4 + 0);
            m |= (d.y ? 1u : 0u) << (c * 4 + 1);
            m |= (d.z ? 1u : 0u) << (c * 4 + 2);
            m |= (d.w ? 1u : 0u) << (c * 4 + 3);
          } else {
            const int* ip = (const int*)adj;
            long ib = ((long)b * NN + j) * NN;
#pragma unroll
            for (int k = 0; k < 4; ++k){
              int i = im + c * 4 + k;
              if (i < NN) m |= (ip[ib + i] ? 1u : 0u) << (c * 4 + k);
            }
          }
        }
      } else {
        const char* p = (const char*)adj;
        long base = (long)b * NN * NN + (long)j * NN + im;
        long lim  = (long)NB * NN * NN;
#pragma unroll
        for (int c = 0; c < 2; ++c){
          long off = base + c * 8;
          if (off + 8 <= lim){
            u64 x = *(const u64*)(p + off);
#pragma unroll
            for (int k = 0; k < 8; ++k)
              m |= (((x >> (8 * k)) & 0xFFull) ? 1u : 0u) << (c * 8 + k);
          } else {
#pragma unroll
            for (int k = 0; k < 8; ++k){
              long o2 = off + k;
              if (o2 < lim) m |= (p[o2] ? 1u : 0u) << (c * 8 + k);
            }
          }
        }
      }
      m &= vmask;
    }
    int s = 4 * lane;
    unsigned a0 = (unsigned)__shfl((int)m, (s + 0) & 63, 64);
    unsigned a1 = (unsigned)__shfl((int)m, (s + 1) & 63, 64);
    unsigned a2 = (unsigned)__shfl((int)m, (s + 2) & 63, 64);
    unsigned a3 = (unsigned)__shfl((int)m, (s + 3) & 63, 64);
    if (lane < 16){
      u64 w = (u64)(a0 & 0xFFFFu) | ((u64)(a1 & 0xFFFFu) << 16)
            | ((u64)(a2 & 0xFFFFu) << 32) | ((u64)(a3 & 0xFFFFu) << 48);
      adjQ[((long)b * 16 + lane) * 1024 + j] = w;
    }
  }
}
template<bool F32>
__device__ void wp_role(const void* Wp, const void* vpd, const void* vpf,
                        short* WpB_hi, short* WpB_lo, float* wv_ws, int rel){
  int t = threadIdx.x;
  int g = t >> 6, lane = t & 63;
  int f = rel * 4 + g;               // 0..159
  float wrow[4];
#pragma unroll
  for (int r = 0; r < 4; ++r){
    int ch = r * 64 + lane;
    wrow[r] = (f < 147) ? ldf<F32>(Wp, (long)f * HIDD + ch) : 0.f;
  }
  int kb = f >> 5, q = (f >> 3) & 3, u = f & 7;
#pragma unroll
  for (int r = 0; r < 4; ++r){
    int ch = r * 64 + lane;
    long off = (((long)(kb * 4 + q)) * 256 + ch) * 8 + u;
    short hi, lo; split_bf(wrow[r], hi, lo);
    WpB_hi[off] = hi; WpB_lo[off] = lo;
  }
  float ad = 0.f, af = 0.f;
#pragma unroll
  for (int r = 0; r < 4; ++r){
    int ch = r * 64 + lane;
    ad += wrow[r] * ldf<F32>(vpd, ch);
    af += wrow[r] * ldf<F32>(vpf, ch);
  }
  ad = wave_bsum(ad); af = wave_bsum(af);
  if (lane == 0){ wv_ws[f] = ad; wv_ws[160 + f] = af; }
}
template<bool F32>
__device__ void wco_role(const void* Wco, const void* asrc, const void* adst,
                         short* WcoB_hi, short* WcoB_lo, float* pvco, int rel){
  int t = threadIdx.x;
  int g = t >> 6, lane = t & 63;
  int f = rel * 4 + g;               // 0..95
  float w = (f < 79) ? ldf<F32>(Wco, (long)f * COMD + lane) : 0.f;
  int kb = f >> 5, q = (f >> 3) & 3, u = f & 7;
  long off = (((long)(kb * 4 + q)) * 64 + lane) * 8 + u;
  short hi, lo; split_bf(w, hi, lo);
  WcoB_hi[off] = hi; WcoB_lo[off] = lo;
  float dd = wave_bsum(w * ldf<F32>(adst, lane));
  float ss = wave_bsum(w * ldf<F32>(asrc, lane));
  if (lane == 0){ pvco[f] = dd; pvco[96 + f] = ss; }
}
template<bool F32>
__device__ void misc_role(const void* wdc, const void* wdco,
                          const void* bp, const void* vpd, const void* vpf,
                          int f32, int as_int,
                          int* flags, float* wd_ws, float* wv_ws){
  int t = threadIdx.x;
  if (t >= 64) return;
  int lane = t;
  float ad = 0.f, af = 0.f;
#pragma unroll
  for (int r = 0; r < 4; ++r){
    int ch = r * 64 + lane;
    float bb = ldf<F32>(bp, ch);
    ad += bb * ldf<F32>(vpd, ch);
    af += bb * ldf<F32>(vpf, ch);
  }
  ad = wave_bsum(ad); af = wave_bsum(af);
  if (lane == 0){
    wv_ws[320] = ad; wv_ws[321] = af;
    wd_ws[0] = ldf<F32>(wdc, 0);
    wd_ws[1] = ldf<F32>(wdco, 0);
    flags[0] = f32; flags[1] = as_int;
  }
}
__global__ void __launch_bounds__(256) k_prep(
    const void* dist, const void* adj_comp, const void* adj_coop,
    const void* wdc, const void* wdco,
    const void* Wp, const void* vpd, const void* vpf, const void* bp,
    const void* Wco, const void* asrc_co, const void* adst_co,
    int* flags, float* wd_ws, bf16* distTb, u64* adjQc, u64* adjQo,
    short* WpB_hi, short* WpB_lo, float* wv_ws,
    short* WcoB_hi, short* WcoB_lo, float* pvco){
  int blk = blockIdx.x;
  int f32, as_int;
  sniff2(dist, adj_comp, threadIdx.x & 63, f32, as_int);
  if (blk < PB_AQ1){
    if (f32) dist_t_role<true >(dist, distTb, blk);
    else     dist_t_role<false>(dist, distTb, blk);
  } else if (blk < PB_AQ2){
    if (as_int) adjq_role<true >(adj_comp, adjQc, blk - PB_AQ1);
    else        adjq_role<false>(adj_comp, adjQc, blk - PB_AQ1);
  } else if (blk < PB_WP){
    if (as_int) adjq_role<true >(adj_coop, adjQo, blk - PB_AQ2);
    else        adjq_role<false>(adj_coop, adjQo, blk - PB_AQ2);
  } else if (blk < PB_WCO){
    if (f32) wp_role<true >(Wp, vpd, vpf, WpB_hi, WpB_lo, wv_ws, blk - PB_WP);
    else     wp_role<false>(Wp, vpd, vpf, WpB_hi, WpB_lo, wv_ws, blk - PB_WP);
  } else if (blk < PB_MISC){
    if (f32) wco_role<true >(Wco, asrc_co, adst_co, WcoB_hi, WcoB_lo, pvco, blk - PB_WCO);
    else     wco_role<false>(Wco, asrc_co, adst_co, WcoB_hi, WcoB_lo, pvco, blk - PB_WCO);
  } else {
    if (f32) misc_role<true >(wdc, wdco, bp, vpd, vpf, f32, as_int, flags, wd_ws, wv_ws);
    else     misc_role<false>(wdc, wdco, bp, vpd, vpf, f32, as_int, flags, wd_ws, wv_ws);
  }
}

// ---------------- embedding + h_c (direct to hB planes) + attn scalars ----------------
template<bool F32>
__device__ __forceinline__ void embed_body(
    const int* op_idx, const void* vf, const void* cs_tab, const void* tp_tab,
    const void* Wc, const void* asrc, const void* adst,
    float* x_out, short* hB_hi, short* hB_lo, float* ed_out, float* es_out){
  int t = threadIdx.x;
  int w = t >> 6, lane = t & 63;
  int g = blockIdx.x * 4 + w;
  int b = g / NN, n = g - b * NN;
  int op = op_idx[g];
  float xv = 0.f, hacc = 0.f;
#pragma unroll
  for (int f = 0; f < 15; ++f){
    float x_f;
    if (f < 4)      x_f = ldf<F32>(cs_tab, n * 4 + f);
    else if (f < 6) x_f = ldf<F32>(tp_tab, op * 2 + (f - 4));
    else            x_f = ldf<F32>(vf, (long)g * 9 + (f - 6));
    if (lane == f) xv = x_f;
    hacc += x_f * ldf<F32>(Wc, f * COMD + lane);
  }
  if (lane < 15) x_out[g * 15 + lane] = xv;
  hB_write(hB_hi, hB_lo, b, n, lane, hacc);
  float sd = wave_sum(hacc * ldf<F32>(adst, lane));
  float ss = wave_sum(hacc * ldf<F32>(asrc, lane));
  if (lane == 0){ ed_out[g] = sd; es_out[g] = ss; }
}
__global__ void __launch_bounds__(256) k_embed(
    const int* flags, const int* op_idx, const void* vf, const void* cs_tab,
    const void* tp_tab, const void* Wc, const void* asrc, const void* adst,
    float* x_out, short* hB_hi, short* hB_lo, float* ed_out, float* es_out){
  if (flags[0]) embed_body<true >(op_idx, vf, cs_tab, tp_tab, Wc, asrc, adst, x_out, hB_hi, hB_lo, ed_out, es_out);
  else          embed_body<false>(op_idx, vf, cs_tab, tp_tab, Wc, asrc, adst, x_out, hB_hi, hB_lo, ed_out, es_out);
}

// ---------------- h_co = [x, comp] @ Wco via MFMA; f32 ed/es dots ----------------
__global__ void __launch_bounds__(256) k_hco(
    const float* __restrict__ x_ws, const float* __restrict__ comp,
    const short* __restrict__ WcoB_hi, const short* __restrict__ WcoB_lo,
    const float* __restrict__ pvco,
    short* hB_hi, short* hB_lo, float* ed_out, float* es_out){
  __shared__ float cx[16][80] __attribute__((aligned(16)));
  __shared__ short cA_hi[3 * 16 * 40] __attribute__((aligned(16)));
  __shared__ short cA_lo[3 * 16 * 40] __attribute__((aligned(16)));
  int t = threadIdx.x;
  int wv = t >> 6, lane = t & 63;
  int base = blockIdx.x * 16;
  for (int idx = t; idx < 16 * 79; idx += 256){
    int nl = idx / 79, f = idx - nl * 79;
    int g = base + nl;
    cx[nl][f] = (f < 15) ? x_ws[g * 15 + f] : comp[(long)g * COMD + (f - 15)];
  }
  __syncthreads();
  {
    int node = t >> 4, sub = t & 15;
    float dd = 0.f, ss = 0.f;
    for (int f = sub; f < 79; f += 16){
      float c = cx[node][f];
      dd += c * pvco[f];
      ss += c * pvco[96 + f];
    }
#pragma unroll
    for (int o = 8; o > 0; o >>= 1){
      dd += __shfl_xor(dd, o, 64);
      ss += __shfl_xor(ss, o, 64);
    }
    if (sub == 0){
      int g = base + node;
      ed_out[g] = dd; es_out[g] = ss;
    }
  }
  for (int idx = t; idx < 16 * 96; idx += 256){
    int m = idx / 96, k = idx - m * 96;
    float v = (k < 79) ? cx[m][k] : 0.f;
    int kb = k >> 5, q = (k >> 3) & 3, u = k & 7;
    short hi, lo; split_bf(v, hi, lo);
    int off = (kb * 16 + m) * 40 + q * 8 + u;
    cA_hi[off] = hi; cA_lo[off] = lo;
  }
  __syncthreads();
  int q = lane >> 4, m = lane & 15;
  int ch = wv * 16 + m;
  f32x4 acc = {0.f, 0.f, 0.f, 0.f};
#pragma unroll
  for (int kb = 0; kb < 3; ++kb){
    int aoff = (kb * 16 + m) * 40 + q * 8;
    s16x8 a_hi = *(const s16x8*)&cA_hi[aoff];
    s16x8 a_lo = *(const s16x8*)&cA_lo[aoff];
    long boff = (((long)(kb * 4 + q)) * 64 + ch) * 8;
    s16x8 b_hi = *(const s16x8*)&WcoB_hi[boff];
    s16x8 b_lo = *(const s16x8*)&WcoB_lo[boff];
    acc = __builtin_amdgcn_mfma_f32_16x16x32_bf16(a_hi, b_hi, acc, 0, 0, 0);
    acc = __builtin_amdgcn_mfma_f32_16x16x32_bf16(a_hi, b_lo, acc, 0, 0, 0);
    acc = __builtin_amdgcn_mfma_f32_16x16x32_bf16(a_lo, b_hi, acc, 0, 0, 0);
  }
#pragma unroll
  for (int reg = 0; reg < 4; ++reg){
    int row = (lane >> 4) * 4 + reg;
    int g = base + row;
    int b = g / NN, n = g - b * NN;
    hB_write(hB_hi, hB_lo, b, n, ch, acc[reg]);
  }
}

// ---------------- masked-softmax GAT: block-local es-max, 2 barriers ----------------
__global__ void __launch_bounds__(256) k_gat(
    const float* __restrict__ ed, const float* __restrict__ es,
    const float* __restrict__ wd_ws, int wd_idx, const u64* __restrict__ adjQ,
    const bf16* __restrict__ distTb,
    const short* __restrict__ hB_hi, const short* __restrict__ hB_lo,
    float* __restrict__ reps){
  __shared__ short pA[32 * 544] __attribute__((aligned(16)));
  __shared__ float redz[TI][4];
  __shared__ float esred[4];
  int t = threadIdx.x;
  int wv = t >> 6, lane = t & 63;
  int b = blockIdx.y;
  int i0 = blockIdx.x * TI;
  float wd = wd_ws[wd_idx];
  int iw = i0 >> 6, sb = i0 & 63;
  int j0 = t * 4;

  const u64* aq = adjQ + ((long)b * 16 + iw) * 1024 + j0;
  u64x2 wA = *(const u64x2*)&aq[0];
  u64x2 wB = *(const u64x2*)&aq[2];
  unsigned wsh[4] = { (unsigned)(wA[0] >> sb), (unsigned)(wA[1] >> sb),
                      (unsigned)(wB[0] >> sb), (unsigned)(wB[1] >> sb) };
  float4 es4 = *(const float4*)&es[(long)b * NN + j0];
  float esv[4] = {es4.x, es4.y, es4.z, es4.w};
  float esm = -1e30f;
#pragma unroll
  for (int c = 0; c < 4; ++c)
    esm = fmaxf(esm, (j0 + c < NN) ? esv[c] : -1e30f);
  esm = wave_bmax(esm);
  if (lane == 0) esred[wv] = esm;

  float ed_i[TI]; float edm = -1e30f;
#pragma unroll
  for (int ti = 0; ti < TI; ++ti){
    int i = i0 + ti;
    float ev = ed[(long)b * NN + ((i < NN) ? i : (NN - 1))];
    ed_i[ti] = ev;
    edm = fmaxf(edm, (i < NN) ? ev : -1e30f);
  }
  __syncthreads();
  float M = fmaxf(fmaxf(esred[0], esred[1]), fmaxf(esred[2], esred[3]))
            + edm + fmaxf(wd, 0.f);
  M = fmaxf(M, 0.f);   // uniform upper bound on all scores; softmax exact

  float p[TI][4];
  const bf16* dbase = distTb + j0;
#pragma unroll
  for (int ti = 0; ti < TI; ++ti){
    int i = i0 + ti;
    int ic = (i < NN) ? i : (NN - 1);
    u16x4 d4 = *(const u16x4*)&dbase[(long)ic * DSTRIDE];
    float edti = ed_i[ti];
#pragma unroll
    for (int c = 0; c < 4; ++c){
      float d = __uint_as_float((unsigned)d4[c] << 16);
      float v = edti + esv[c] + wd * d;
      v = fmaxf(v, 0.2f * v);                 // leaky_relu
      bool edge = (wsh[c] >> ti) & 1u;
      float e = edge ? v : -1e30f;
      p[ti][c] = __expf(e - M);
    }
  }

  int kbw = 8 * wv + (lane >> 3);
  int qw = (lane >> 1) & 3;
  int u0 = 4 * (lane & 1);
  int wbase = kbw * 544 + qw * 136 + u0;
#pragma unroll
  for (int ti = 0; ti < TI; ++ti){
    float zs = p[ti][0] + p[ti][1] + p[ti][2] + p[ti][3];
    zs = wave_bsum(zs);
    if (lane == 0) redz[ti][wv] = zs;
    s16x4 s4 = { f2bs(p[ti][0]), f2bs(p[ti][1]), f2bs(p[ti][2]), f2bs(p[ti][3]) };
    *(s16x4*)&pA[wbase + ti * 8] = s4;
  }
  __syncthreads();

  int q = lane >> 4, m = lane & 15;
  int abase = q * 136 + m * 8;
  int ch = wv * 16 + m;
  const short* bh = hB_hi + (long)b * 65536 + ((long)q * 64 + ch) * 8;
  const short* bl = hB_lo + (long)b * 65536 + ((long)q * 64 + ch) * 8;
  f32x4 acc = {0.f, 0.f, 0.f, 0.f};
#pragma unroll
  for (int kb = 0; kb < 32; ++kb){
    s16x8 a   = *(const s16x8*)&pA[kb * 544 + abase];
    s16x8 bhi = *(const s16x8*)&bh[(long)kb * 2048];
    s16x8 blo = *(const s16x8*)&bl[(long)kb * 2048];
    acc = __builtin_amdgcn_mfma_f32_16x16x32_bf16(a, bhi, acc, 0, 0, 0);
    acc = __builtin_amdgcn_mfma_f32_16x16x32_bf16(a, blo, acc, 0, 0, 0);
  }
#pragma unroll
  for (int reg = 0; reg < 4; ++reg){
    int ti = (lane >> 4) * 4 + reg;
    float z = redz[ti][0] + redz[ti][1] + redz[ti][2] + redz[ti][3];
    float zi = (z > 0.f) ? 1.f / z : 0.f;
    float v = acc[reg] * zi;
    v = (v > 0.f) ? v : expm1f(v);
    int ch2 = wv * 16 + (lane & 15);
    if (i0 + ti < NN)
      reps[((long)b * NN + i0 + ti) * COMD + ch2] = v;
  }
}

// ---------------- x_p = sag@Wp + bp via MFMA; f32 fused scores ----------------
template<bool F32>
__device__ __forceinline__ void xp_body(
    const int* time_idx, const int* op_idx, const void* vf, const void* time_tab,
    const void* cs_tab, const void* tp_tab, const float* comp, const float* coop,
    const short* __restrict__ WpB_hi, const short* __restrict__ WpB_lo,
    const float* __restrict__ wv_ws, const void* bp,
    float* x_p, float* scf, float* scd){
  __shared__ float sagF[16][148] __attribute__((aligned(16)));
  __shared__ short sagA_hi[5 * 16 * 40] __attribute__((aligned(16)));
  __shared__ short sagA_lo[5 * 16 * 40] __attribute__((aligned(16)));
  int t = threadIdx.x;
  int wv = t >> 6, lane = t & 63;
  int base = blockIdx.x * 16;

  for (int idx = t; idx < 16 * 147; idx += 256){
    int nl = idx / 147, f = idx - nl * 147;
    int g = base + nl;
    int n = g % NN;
    float v;
    if (f < 4)       v = ldf<F32>(time_tab, time_idx[g] * 4 + f);
    else if (f < 8)  v = ldf<F32>(cs_tab, n * 4 + (f - 4));
    else if (f < 10) v = ldf<F32>(tp_tab, op_idx[g] * 2 + (f - 8));
    else if (f < 19) v = ldf<F32>(vf, (long)g * 9 + (f - 10));
    else if (f < 83) v = comp[(long)g * COMD + (f - 19)];
    else             v = coop[(long)g * COMD + (f - 83)];
    sagF[nl][f] = v;
  }
  __syncthreads();

  for (int idx = t; idx < 16 * 160; idx += 256){
    int m = idx / 160, k = idx - m * 160;
    float v = (k < 147) ? sagF[m][k] : 0.f;
    int kb = k >> 5, q = (k >> 3) & 3, u = k & 7;
    short hi, lo; split_bf(v, hi, lo);
    int off = (kb * 16 + m) * 40 + q * 8 + u;
    sagA_hi[off] = hi; sagA_lo[off] = lo;
  }
  {
    int node = t >> 4, sub = t & 15;
    float ad = 0.f, af = 0.f;
    for (int f = sub; f < 147; f += 16){
      float s = sagF[node][f];
      ad += s * wv_ws[f];
      af += s * wv_ws[160 + f];
    }
#pragma unroll
    for (int o = 8; o > 0; o >>= 1){
      ad += __shfl_xor(ad, o, 64);
      af += __shfl_xor(af, o, 64);
    }
    if (sub == 0){
      scd[base + node] = ad + wv_ws[320];
      scf[base + node] = af + wv_ws[321];
    }
  }
  __syncthreads();

  int Ag = lane >> 4, Am = lane & 15;
  f32x4 acc[4] = {{0,0,0,0},{0,0,0,0},{0,0,0,0},{0,0,0,0}};
#pragma unroll
  for (int kb = 0; kb < 5; ++kb){
    int aoff = (kb * 16 + Am) * 40 + Ag * 8;
    s16x8 a_hi = *(const s16x8*)&sagA_hi[aoff];
    s16x8 a_lo = *(const s16x8*)&sagA_lo[aoff];
#pragma unroll
    for (int ct = 0; ct < 4; ++ct){
      int ch = wv * 64 + ct * 16 + Am;
      long boff = (((long)(kb * 4 + Ag)) * 256 + ch) * 8;
      s16x8 b_hi = *(const s16x8*)&WpB_hi[boff];
      s16x8 b_lo = *(const s16x8*)&WpB_lo[boff];
      acc[ct] = __builtin_amdgcn_mfma_f32_16x16x32_bf16(a_hi, b_hi, acc[ct], 0, 0, 0);
      acc[ct] = __builtin_amdgcn_mfma_f32_16x16x32_bf16(a_hi, b_lo, acc[ct], 0, 0, 0);
      acc[ct] = __builtin_amdgcn_mfma_f32_16x16x32_bf16(a_lo, b_hi, acc[ct], 0, 0, 0);
    }
  }
#pragma unroll
  for (int ct = 0; ct < 4; ++ct){
    int ch = wv * 64 + ct * 16 + (lane & 15);
    float bb = ldf<F32>(bp, ch);
#pragma unroll
    for (int reg = 0; reg < 4; ++reg){
      int row = (lane >> 4) * 4 + reg;
      x_p[(long)(base + row) * HIDD + ch] = acc[ct][reg] + bb;
    }
  }
}
__global__ void __launch_bounds__(256) k_xp(
    const int* flags, const int* time_idx, const int* op_idx, const void* vf,
    const void* time_tab, const void* cs_tab, const void* tp_tab,
    const float* comp, const float* coop,
    const short* WpB_hi, const short* WpB_lo, const float* wv_ws, const void* bp,
    float* x_p, float* scf, float* scd){
  if (flags[0]) xp_body<true >(time_idx, op_idx, vf, time_tab, cs_tab, tp_tab, comp, coop, WpB_hi, WpB_lo, wv_ws, bp, x_p, scf, scd);
  else          xp_body<false>(time_idx, op_idx, vf, time_tab, cs_tab, tp_tab, comp, coop, WpB_hi, WpB_lo, wv_ws, bp, x_p, scf, scd);
}

// ---------------- top-k weights: one wave per (b,pool) ----------------
template<bool BINT>
__device__ __forceinline__ void topk_body(
    const float* scf, const float* scd, const void* mark, float* wls){
  int lane = threadIdx.x;
  int b = blockIdx.x, pool = blockIdx.y;
  const float* sc = (pool == 0) ? scf : scd;
  float v[16]; unsigned key[16];
  float m0 = -INFINITY;
#pragma unroll
  for (int r = 0; r < 16; ++r){
    int n = r * 64 + lane;
    float s = (n < NN) ? sc[b * NN + n] : -INFINITY;
    v[r] = s;
    m0 = fmaxf(m0, s);
  }
  m0 = wave_bmax(m0);
  float m1 = -INFINITY;
#pragma unroll
  for (int r = 0; r < 16; ++r){
    int n = r * 64 + lane;
    bool valid = false;
    if (n < NN){
      bool mk = ldb<BINT>(mark, b * NN + n);
      valid = (pool == 0) ? !mk : mk;
    }
    v[r] = valid ? (v[r] - m0) : -1e8f;
    key[r] = fkey(v[r]);
    if (n < NN) m1 = fmaxf(m1, v[r]);
  }
  m1 = wave_bmax(m1);

  unsigned lo = 0u, hi = 0xFFFFFFFFu;
  while (lo < hi){
    unsigned mid = lo + ((hi - lo) >> 1) + 1u;
    int c = 0;
#pragma unroll
    for (int r = 0; r < 16; ++r) c += (key[r] >= mid) ? 1 : 0;
    c = wave_bsum_i(c);
    if (c >= KSEL) lo = mid; else hi = mid - 1u;
  }

  float p[16];
  float ls = 0.f;
#pragma unroll
  for (int r = 0; r < 16; ++r){
    int n = r * 64 + lane;
    float pp = (n < NN && key[r] >= lo) ? __expf(v[r] - m1) : 0.f;
    p[r] = pp;
    ls += pp;
  }
  ls = wave_bsum(ls);
  float zinv = (ls > 0.f) ? 1.f / ls : 0.f;
  float* w_out = wls + ((long)b * 2 + pool) * 1024;
#pragma unroll
  for (int r = 0; r < 16; ++r){
    int n = r * 64 + lane;
    if (n < NN) w_out[n] = p[r] * zinv;
  }
}
__global__ void k_topk(const int* flags, const float* scf, const float* scd,
                       const void* mark, float* wls){
  if (flags[1]) topk_body<true >(scf, scd, mark, wls);
  else          topk_body<false>(scf, scd, mark, wls);
}

// ---------------- gated partial sums ----------------
__global__ void __launch_bounds__(256) k_psum(
    const float* __restrict__ wls, const float* __restrict__ x_p,
    float* __restrict__ part){
  __shared__ float wf[ROWS], wdd[ROWS];
  int t = threadIdx.x;
  int b = blockIdx.x, z = blockIdx.y;
  int n0 = z * ROWS;
  int ns = min(ROWS, NN - n0);
  if (t < ns){
    wf[t]  = wls[((long)b * 2 + 0) * 1024 + n0 + t];
    wdd[t] = wls[((long)b * 2 + 1) * 1024 + n0 + t];
  }
  __syncthreads();
  float sf = 0.f, mf = -INFINITY, sd = 0.f, md = -INFINITY;
  const float* xb = x_p + ((long)b * NN + n0) * HIDD + t;
  for (int k = 0; k < ns; ++k){
    float xv = xb[(long)k * HIDD];
    float gf = wf[k] * xv;
    float gd = wdd[k] * xv;
    sf += gf; mf = fmaxf(mf, gf);
    sd += gd; md = fmaxf(md, gd);
  }
  long pb = (((long)b * NSPL + z) * 4) * HIDD + t;
  part[pb + 0 * HIDD] = sf;
  part[pb + 1 * HIDD] = mf;
  part[pb + 2 * HIDD] = sd;
  part[pb + 3 * HIDD] = md;
}

// ---------------- final reduce ----------------
template<bool F32>
__device__ __forceinline__ void pfin_body(const float* part, void* out){
  int t = threadIdx.x;
  int b = blockIdx.x;
  float sf = 0.f, mf = -INFINITY, sd = 0.f, md = -INFINITY;
#pragma unroll
  for (int z = 0; z < NSPL; ++z){
    long pb = (((long)b * NSPL + z) * 4) * HIDD + t;
    sf += part[pb + 0 * HIDD];
    mf = fmaxf(mf, part[pb + 1 * HIDD]);
    sd += part[pb + 2 * HIDD];
    md = fmaxf(md, part[pb + 3 * HIDD]);
  }
  long ob = (long)b * 1024;
  if (F32){
    ((float*)out)[ob + t] = sf;
    ((float*)out)[ob + 256 + t] = mf;
    ((float*)out)[ob + 512 + t] = sd;
    ((float*)out)[ob + 768 + t] = md;
  } else {
    ((bf16*)out)[ob + t] = __float2bfloat16(sf);
    ((bf16*)out)[ob + 256 + t] = __float2bfloat16(mf);
    ((bf16*)out)[ob + 512 + t] = __float2bfloat16(sd);
    ((bf16*)out)[ob + 768 + t] = __float2bfloat16(md);
  }
}
__global__ void k_pfin(const int* flags, const float* part, void* out){
  if (flags[0]) pfin_body<true >(part, out);
  else          pfin_body<false>(part, out);
}

extern "C" void kernel_launch(void* const* d_in, const int* in_sizes, int n_in,
                              void* d_out, int out_size, void* d_ws, size_t ws_size,
                              hipStream_t stream){
  const int*  time_idx = (const int*)d_in[0];
  const int*  op_idx   = (const int*)d_in[1];
  const void* vfeat    = d_in[2];
  const void* dpcs     = d_in[3];
  const void* adj_comp = d_in[4];
  const void* adj_coop = d_in[5];
  const void* dist     = d_in[6];
  const void* time_tab = d_in[7];
  const void* tp_tab   = d_in[8];
  const void* cs_tab   = d_in[9];
  const void* Wc       = d_in[10];
  const void* asrc_c   = d_in[11];
  const void* adst_c   = d_in[12];
  const void* wd_c     = d_in[13];
  const void* Wco      = d_in[14];
  const void* asrc_co  = d_in[15];
  const void* adst_co  = d_in[16];
  const void* wd_co    = d_in[17];
  const void* Wp       = d_in[18];
  const void* bp       = d_in[19];
  const void* vpd      = d_in[20];
  const void* vpf      = d_in[21];

  char* ws = (char*)d_ws;
  size_t o = 0;
  auto alloc = [&](size_t bytes)->char*{
    char* p = ws + o; o = (o + bytes + 255) & ~(size_t)255; return p;
  };
  int*   flags   = (int*)alloc(16);
  float* wd_ws   = (float*)alloc(8);
  bf16*  distTb  = (bf16*)alloc((size_t)NN * DSTRIDE * 2);
  u64*   adjQc   = (u64*)alloc((size_t)NB * 16 * 1024 * 8);
  u64*   adjQo   = (u64*)alloc((size_t)NB * 16 * 1024 * 8);
  float* x_ws    = (float*)alloc((size_t)NB * NN * 15 * 4);
  float* comp    = (float*)alloc((size_t)NB * NN * COMD * 4);
  float* coop    = (float*)alloc((size_t)NB * NN * COMD * 4);
  short* hB_hi   = (short*)alloc((size_t)NB * 65536 * 2);
  short* hB_lo   = (short*)alloc((size_t)NB * 65536 * 2);
  short* WpB_hi  = (short*)alloc((size_t)5 * 4 * 256 * 8 * 2);
  short* WpB_lo  = (short*)alloc((size_t)5 * 4 * 256 * 8 * 2);
  short* WcoB_hi = (short*)alloc((size_t)3 * 4 * 64 * 8 * 2);
  short* WcoB_lo = (short*)alloc((size_t)3 * 4 * 64 * 8 * 2);
  float* wv_ws   = (float*)alloc(322 * 4);
  float* pvco    = (float*)alloc(192 * 4);
  float* ed_c    = (float*)alloc((size_t)NB * NN * 4 + 256);
  float* es_c    = (float*)alloc((size_t)NB * NN * 4 + 256);
  float* ed_o    = (float*)alloc((size_t)NB * NN * 4 + 256);
  float* es_o    = (float*)alloc((size_t)NB * NN * 4 + 256);
  float* scf     = (float*)alloc((size_t)NB * NN * 4);
  float* scd     = (float*)alloc((size_t)NB * NN * 4);
  float* wls     = (float*)alloc((size_t)NB * 2 * 1024 * 4);
  float* part    = (float*)alloc((size_t)NB * NSPL * 4 * HIDD * 4);
  float* x_p     = (float*)alloc((size_t)NB * NN * HIDD * 4);

  k_prep<<<dim3(PB_N), dim3(256), 0, stream>>>(
      dist, adj_comp, adj_coop, wd_c, wd_co, Wp, vpd, vpf, bp,
      Wco, asrc_co, adst_co,
      flags, wd_ws, distTb, adjQc, adjQo, WpB_hi, WpB_lo, wv_ws,
      WcoB_hi, WcoB_lo, pvco);
  k_embed<<<dim3(NB * NN / 4), dim3(256), 0, stream>>>(
      flags, op_idx, vfeat, cs_tab, tp_tab, Wc, asrc_c, adst_c,
      x_ws, hB_hi, hB_lo, ed_c, es_c);
  k_gat<<<dim3((NN + TI - 1) / TI, NB), dim3(256), 0, stream>>>(
      ed_c, es_c, wd_ws, 0, adjQc, distTb, hB_hi, hB_lo, comp);
  k_hco<<<dim3(NB * NN / 16), dim3(256), 0, stream>>>(
      x_ws, comp, WcoB_hi, WcoB_lo, pvco, hB_hi, hB_lo, ed_o, es_o);
  k_gat<<<dim3((NN + TI - 1) / TI, NB), dim3(256), 0, stream>>>(
      ed_o, es_o, wd_ws, 1, adjQo, distTb, hB_hi, hB_lo, coop);
  k_xp<<<dim3(NB * NN / 16), dim3(256), 0, stream>>>(
      flags, time_idx, op_idx, vfeat, time_tab, cs_tab, tp_tab, comp, coop,
      WpB_hi, WpB_lo, wv_ws, bp, x_p, scf, scd);
  k_topk<<<dim3(NB, 2), dim3(64), 0, stream>>>(flags, scf, scd, dpcs, wls);
  k_psum<<<dim3(NB, NSPL), dim3(256), 0, stream>>>(wls, x_p, part);
  k_pfin<<<dim3(NB), dim3(256), 0, stream>>>(flags, part, d_out);
}

// Round 12
// 503.835 us; speedup vs baseline: 1.0255x; 1.0255x over previous
//
#include <hip/hip_runtime.h>
#include <hip/hip_bf16.h>

#define NB 32
#define NN 1000
#define COMD 64
#define HIDD 256
#define KSEL 500
#define TI 16        // dst rows per k_gat block
#define NSPL 32      // n-splits for k_psum
#define ROWS 32      // ceil(NN/NSPL)
#define DSTRIDE 1024 // padded distT row stride

// k_prep role bases
#define PB_DT   0        // 256 dist-transpose tiles
#define PB_AQ1  256      // 1024 adjq comp   (32 j's per block)
#define PB_AQ2  1280     // 1024 adjq coop
#define PB_WP   2304     // 40 blocks x 4 rows = 160 Wp rows
#define PB_WCO  2344     // 24 blocks x 4 rows = 96 Wco rows
#define PB_MISC 2368     // flags, wd, bias dots
#define PB_N    2369

typedef __hip_bfloat16 bf16;
typedef unsigned long long u64;
typedef __attribute__((ext_vector_type(4))) float f32x4;
typedef __attribute__((ext_vector_type(8))) short s16x8;
typedef __attribute__((ext_vector_type(4))) short s16x4;
typedef __attribute__((ext_vector_type(4))) unsigned short u16x4;
typedef __attribute__((ext_vector_type(2))) unsigned long long u64x2;

__device__ __forceinline__ float b2f(bf16 x){ return __bfloat162float(x); }

template<bool F32>
__device__ __forceinline__ float ldf(const void* p, long i){
  return F32 ? ((const float*)p)[i] : b2f(((const bf16*)p)[i]);
}
template<bool BINT>
__device__ __forceinline__ bool ldb(const void* p, long i){
  return BINT ? (((const int*)p)[i] != 0) : (((const unsigned char*)p)[i] != 0);
}

__device__ __forceinline__ float wave_sum(float v){
#pragma unroll
  for (int o = 32; o > 0; o >>= 1) v += __shfl_down(v, o, 64);
  return v;
}
__device__ __forceinline__ float wave_bsum(float v){
#pragma unroll
  for (int o = 32; o > 0; o >>= 1) v += __shfl_xor(v, o, 64);
  return v;
}
__device__ __forceinline__ float wave_bmax(float v){
#pragma unroll
  for (int o = 32; o > 0; o >>= 1) v = fmaxf(v, __shfl_xor(v, o, 64));
  return v;
}
__device__ __forceinline__ int wave_bsum_i(int v){
#pragma unroll
  for (int o = 32; o > 0; o >>= 1) v += __shfl_xor(v, o, 64);
  return v;
}
__device__ __forceinline__ unsigned fkey(float f){
  unsigned u = __float_as_uint(f);
  return (u & 0x80000000u) ? ~u : (u | 0x80000000u);
}
// split fp32 into bf16 hi + bf16 lo with v ≈ hi + lo (residual ~2^-16 rel)
__device__ __forceinline__ void split_bf(float v, short& hi, short& lo){
  unsigned u = __float_as_uint(v);
  float hf = __uint_as_float(u & 0xFFFF0000u);
  hi = (short)(u >> 16);
  float r = v - hf;                 // exact
  lo = (short)(__float_as_uint(r) >> 16);
}
__device__ __forceinline__ short f2bs(float v){
  bf16 h = __float2bfloat16(v);
  short s; __builtin_memcpy(&s, &h, 2); return s;
}
__device__ __forceinline__ void hB_write(short* hB_hi, short* hB_lo,
                                         int b, int n, int ch, float v){
  int kb = n >> 5, g4 = (n >> 3) & 3, u = n & 7;
  long off = ((((long)b * 32 + kb) * 4 + g4) * 64 + ch) * 8 + u;
  short hi, lo; split_bf(v, hi, lo);
  hB_hi[off] = hi; hB_lo[off] = lo;
}
// cheap per-block dtype sniff: 2 loads + 2 ballots
__device__ __forceinline__ void sniff2(const void* dist, const void* adjc,
                                       int lane, int& f32, int& as_int){
  unsigned wdist = ((const unsigned*)dist)[lane];
  unsigned wadj  = ((const unsigned*)adjc)[lane];
  f32 = (__ballot((wdist & 0xFFFFu) >= 0x8000u) != 0ull) ? 1 : 0;
  as_int = (__ballot(wadj > 1u) == 0ull) ? 1 : 0;
}

// ================ k_prep: all input preprocessing in ONE kernel ================
template<bool F32>
__device__ void dist_t_role(const void* dist, bf16* distTb, int rel){
  __shared__ bf16 tile[64][68];
  int t = threadIdx.x;
  int wv = t >> 6, lane = t & 63;
  int it = (rel & 15) * 64, jt = (rel >> 4) * 64;
#pragma unroll
  for (int r = 0; r < 16; ++r){
    int jl = r * 4 + wv;
    int j = jt + jl, i = it + lane;
    float v = (j < NN && i < NN) ? ldf<F32>(dist, (long)j * NN + i) : 0.f;
    tile[jl][lane] = __float2bfloat16(v);
  }
  __syncthreads();
#pragma unroll
  for (int r = 0; r < 16; ++r){
    int il = r * 4 + wv;
    int i = it + il, j = jt + lane;
    if (i < NN) distTb[(long)i * DSTRIDE + j] = tile[lane][il];
  }
}
// adjacency pack v3: contiguous row reads (v2) + LDS-staged COALESCED writes.
// v2's scattered 8B stores caused write-allocate thrash (FETCH 128->220MB,
// WRITE 10->37MB). Words now staged in padded LDS and written out with
// consecutive threads -> consecutive addresses (full lines, one pass).
template<bool BINT>
__device__ void adjq_role(const void* adj, u64* adjQ, int rel){
  __shared__ u64 aw[16][33];         // +1 pad: 2-way bank alias only (free)
  int t = threadIdx.x;
  int wv = t >> 6, lane = t & 63;
  int j0 = (rel & 31) * 32;
  int b  = rel >> 5;
  int im = lane * 16;
  unsigned vmask = (im >= NN) ? 0u
                 : ((NN - im >= 16) ? 0xFFFFu : ((1u << (NN - im)) - 1u));
#pragma unroll
  for (int r = 0; r < 8; ++r){
    int j = j0 + wv * 8 + r;
    unsigned m = 0;
    if (j < NN){
      if (BINT){
        const char* p = (const char*)adj;
        long base = (((long)b * NN + j) * NN + im) * 4;
        long lim  = (long)NB * NN * NN * 4;
#pragma unroll
        for (int c = 0; c < 4; ++c){
          long off = base + c * 16;
          if (off + 16 <= lim){
            uint4 d = *(const uint4*)(p + off);
            m |= (d.x ? 1u : 0u) << (c * 4 + 0);
            m |= (d.y ? 1u : 0u) << (c * 4 + 1);
            m |= (d.z ? 1u : 0u) << (c * 4 + 2);
            m |= (d.w ? 1u : 0u) << (c * 4 + 3);
          } else {
            const int* ip = (const int*)adj;
            long ib = ((long)b * NN + j) * NN;
#pragma unroll
            for (int k = 0; k < 4; ++k){
              int i = im + c * 4 + k;
              if (i < NN) m |= (ip[ib + i] ? 1u : 0u) << (c * 4 + k);
            }
          }
        }
      } else {
        const char* p = (const char*)adj;
        long base = (long)b * NN * NN + (long)j * NN + im;
        long lim  = (long)NB * NN * NN;
#pragma unroll
        for (int c = 0; c < 2; ++c){
          long off = base + c * 8;
          if (off + 8 <= lim){
            u64 x = *(const u64*)(p + off);
#pragma unroll
            for (int k = 0; k < 8; ++k)
              m |= (((x >> (8 * k)) & 0xFFull) ? 1u : 0u) << (c * 8 + k);
          } else {
#pragma unroll
            for (int k = 0; k < 8; ++k){
              long o2 = off + k;
              if (o2 < lim) m |= (p[o2] ? 1u : 0u) << (c * 8 + k);
            }
          }
        }
      }
      m &= vmask;
    }
    int s = 4 * lane;
    unsigned a0 = (unsigned)__shfl((int)m, (s + 0) & 63, 64);
    unsigned a1 = (unsigned)__shfl((int)m, (s + 1) & 63, 64);
    unsigned a2 = (unsigned)__shfl((int)m, (s + 2) & 63, 64);
    unsigned a3 = (unsigned)__shfl((int)m, (s + 3) & 63, 64);
    if (lane < 16){
      u64 w = (u64)(a0 & 0xFFFFu) | ((u64)(a1 & 0xFFFFu) << 16)
            | ((u64)(a2 & 0xFFFFu) << 32) | ((u64)(a3 & 0xFFFFu) << 48);
      aw[lane][wv * 8 + r] = w;
    }
  }
  __syncthreads();
  // coalesced write-out: 512 words, consecutive threads -> consecutive addrs
#pragma unroll
  for (int rr = 0; rr < 2; ++rr){
    int w2 = t + rr * 256;           // 0..511
    int iw = w2 >> 5, jloc = w2 & 31;
    adjQ[((long)b * 16 + iw) * 1024 + j0 + jloc] = aw[iw][jloc];
  }
}
template<bool F32>
__device__ void wp_role(const void* Wp, const void* vpd, const void* vpf,
                        short* WpB_hi, short* WpB_lo, float* wv_ws, int rel){
  int t = threadIdx.x;
  int g = t >> 6, lane = t & 63;
  int f = rel * 4 + g;               // 0..159
  float wrow[4];
#pragma unroll
  for (int r = 0; r < 4; ++r){
    int ch = r * 64 + lane;
    wrow[r] = (f < 147) ? ldf<F32>(Wp, (long)f * HIDD + ch) : 0.f;
  }
  int kb = f >> 5, q = (f >> 3) & 3, u = f & 7;
#pragma unroll
  for (int r = 0; r < 4; ++r){
    int ch = r * 64 + lane;
    long off = (((long)(kb * 4 + q)) * 256 + ch) * 8 + u;
    short hi, lo; split_bf(wrow[r], hi, lo);
    WpB_hi[off] = hi; WpB_lo[off] = lo;
  }
  float ad = 0.f, af = 0.f;
#pragma unroll
  for (int r = 0; r < 4; ++r){
    int ch = r * 64 + lane;
    ad += wrow[r] * ldf<F32>(vpd, ch);
    af += wrow[r] * ldf<F32>(vpf, ch);
  }
  ad = wave_bsum(ad); af = wave_bsum(af);
  if (lane == 0){ wv_ws[f] = ad; wv_ws[160 + f] = af; }
}
template<bool F32>
__device__ void wco_role(const void* Wco, const void* asrc, const void* adst,
                         short* WcoB_hi, short* WcoB_lo, float* pvco, int rel){
  int t = threadIdx.x;
  int g = t >> 6, lane = t & 63;
  int f = rel * 4 + g;               // 0..95
  float w = (f < 79) ? ldf<F32>(Wco, (long)f * COMD + lane) : 0.f;
  int kb = f >> 5, q = (f >> 3) & 3, u = f & 7;
  long off = (((long)(kb * 4 + q)) * 64 + lane) * 8 + u;
  short hi, lo; split_bf(w, hi, lo);
  WcoB_hi[off] = hi; WcoB_lo[off] = lo;
  float dd = wave_bsum(w * ldf<F32>(adst, lane));
  float ss = wave_bsum(w * ldf<F32>(asrc, lane));
  if (lane == 0){ pvco[f] = dd; pvco[96 + f] = ss; }
}
template<bool F32>
__device__ void misc_role(const void* wdc, const void* wdco,
                          const void* bp, const void* vpd, const void* vpf,
                          int f32, int as_int,
                          int* flags, float* wd_ws, float* wv_ws){
  int t = threadIdx.x;
  if (t >= 64) return;
  int lane = t;
  float ad = 0.f, af = 0.f;
#pragma unroll
  for (int r = 0; r < 4; ++r){
    int ch = r * 64 + lane;
    float bb = ldf<F32>(bp, ch);
    ad += bb * ldf<F32>(vpd, ch);
    af += bb * ldf<F32>(vpf, ch);
  }
  ad = wave_bsum(ad); af = wave_bsum(af);
  if (lane == 0){
    wv_ws[320] = ad; wv_ws[321] = af;
    wd_ws[0] = ldf<F32>(wdc, 0);
    wd_ws[1] = ldf<F32>(wdco, 0);
    flags[0] = f32; flags[1] = as_int;
  }
}
__global__ void __launch_bounds__(256) k_prep(
    const void* dist, const void* adj_comp, const void* adj_coop,
    const void* wdc, const void* wdco,
    const void* Wp, const void* vpd, const void* vpf, const void* bp,
    const void* Wco, const void* asrc_co, const void* adst_co,
    int* flags, float* wd_ws, bf16* distTb, u64* adjQc, u64* adjQo,
    short* WpB_hi, short* WpB_lo, float* wv_ws,
    short* WcoB_hi, short* WcoB_lo, float* pvco){
  int blk = blockIdx.x;
  int f32, as_int;
  sniff2(dist, adj_comp, threadIdx.x & 63, f32, as_int);
  if (blk < PB_AQ1){
    if (f32) dist_t_role<true >(dist, distTb, blk);
    else     dist_t_role<false>(dist, distTb, blk);
  } else if (blk < PB_AQ2){
    if (as_int) adjq_role<true >(adj_comp, adjQc, blk - PB_AQ1);
    else        adjq_role<false>(adj_comp, adjQc, blk - PB_AQ1);
  } else if (blk < PB_WP){
    if (as_int) adjq_role<true >(adj_coop, adjQo, blk - PB_AQ2);
    else        adjq_role<false>(adj_coop, adjQo, blk - PB_AQ2);
  } else if (blk < PB_WCO){
    if (f32) wp_role<true >(Wp, vpd, vpf, WpB_hi, WpB_lo, wv_ws, blk - PB_WP);
    else     wp_role<false>(Wp, vpd, vpf, WpB_hi, WpB_lo, wv_ws, blk - PB_WP);
  } else if (blk < PB_MISC){
    if (f32) wco_role<true >(Wco, asrc_co, adst_co, WcoB_hi, WcoB_lo, pvco, blk - PB_WCO);
    else     wco_role<false>(Wco, asrc_co, adst_co, WcoB_hi, WcoB_lo, pvco, blk - PB_WCO);
  } else {
    if (f32) misc_role<true >(wdc, wdco, bp, vpd, vpf, f32, as_int, flags, wd_ws, wv_ws);
    else     misc_role<false>(wdc, wdco, bp, vpd, vpf, f32, as_int, flags, wd_ws, wv_ws);
  }
}

// ---------------- embedding + h_c (direct to hB planes) + attn scalars ----------------
template<bool F32>
__device__ __forceinline__ void embed_body(
    const int* op_idx, const void* vf, const void* cs_tab, const void* tp_tab,
    const void* Wc, const void* asrc, const void* adst,
    float* x_out, short* hB_hi, short* hB_lo, float* ed_out, float* es_out){
  int t = threadIdx.x;
  int w = t >> 6, lane = t & 63;
  int g = blockIdx.x * 4 + w;
  int b = g / NN, n = g - b * NN;
  int op = op_idx[g];
  float xv = 0.f, hacc = 0.f;
#pragma unroll
  for (int f = 0; f < 15; ++f){
    float x_f;
    if (f < 4)      x_f = ldf<F32>(cs_tab, n * 4 + f);
    else if (f < 6) x_f = ldf<F32>(tp_tab, op * 2 + (f - 4));
    else            x_f = ldf<F32>(vf, (long)g * 9 + (f - 6));
    if (lane == f) xv = x_f;
    hacc += x_f * ldf<F32>(Wc, f * COMD + lane);
  }
  if (lane < 15) x_out[g * 15 + lane] = xv;
  hB_write(hB_hi, hB_lo, b, n, lane, hacc);
  float sd = wave_sum(hacc * ldf<F32>(adst, lane));
  float ss = wave_sum(hacc * ldf<F32>(asrc, lane));
  if (lane == 0){ ed_out[g] = sd; es_out[g] = ss; }
}
__global__ void __launch_bounds__(256) k_embed(
    const int* flags, const int* op_idx, const void* vf, const void* cs_tab,
    const void* tp_tab, const void* Wc, const void* asrc, const void* adst,
    float* x_out, short* hB_hi, short* hB_lo, float* ed_out, float* es_out){
  if (flags[0]) embed_body<true >(op_idx, vf, cs_tab, tp_tab, Wc, asrc, adst, x_out, hB_hi, hB_lo, ed_out, es_out);
  else          embed_body<false>(op_idx, vf, cs_tab, tp_tab, Wc, asrc, adst, x_out, hB_hi, hB_lo, ed_out, es_out);
}

// ---------------- h_co = [x, comp] @ Wco via MFMA; f32 ed/es dots ----------------
__global__ void __launch_bounds__(256) k_hco(
    const float* __restrict__ x_ws, const float* __restrict__ comp,
    const short* __restrict__ WcoB_hi, const short* __restrict__ WcoB_lo,
    const float* __restrict__ pvco,
    short* hB_hi, short* hB_lo, float* ed_out, float* es_out){
  __shared__ float cx[16][80] __attribute__((aligned(16)));
  __shared__ short cA_hi[3 * 16 * 40] __attribute__((aligned(16)));
  __shared__ short cA_lo[3 * 16 * 40] __attribute__((aligned(16)));
  int t = threadIdx.x;
  int wv = t >> 6, lane = t & 63;
  int base = blockIdx.x * 16;
  for (int idx = t; idx < 16 * 79; idx += 256){
    int nl = idx / 79, f = idx - nl * 79;
    int g = base + nl;
    cx[nl][f] = (f < 15) ? x_ws[g * 15 + f] : comp[(long)g * COMD + (f - 15)];
  }
  __syncthreads();
  {
    int node = t >> 4, sub = t & 15;
    float dd = 0.f, ss = 0.f;
    for (int f = sub; f < 79; f += 16){
      float c = cx[node][f];
      dd += c * pvco[f];
      ss += c * pvco[96 + f];
    }
#pragma unroll
    for (int o = 8; o > 0; o >>= 1){
      dd += __shfl_xor(dd, o, 64);
      ss += __shfl_xor(ss, o, 64);
    }
    if (sub == 0){
      int g = base + node;
      ed_out[g] = dd; es_out[g] = ss;
    }
  }
  for (int idx = t; idx < 16 * 96; idx += 256){
    int m = idx / 96, k = idx - m * 96;
    float v = (k < 79) ? cx[m][k] : 0.f;
    int kb = k >> 5, q = (k >> 3) & 3, u = k & 7;
    short hi, lo; split_bf(v, hi, lo);
    int off = (kb * 16 + m) * 40 + q * 8 + u;
    cA_hi[off] = hi; cA_lo[off] = lo;
  }
  __syncthreads();
  int q = lane >> 4, m = lane & 15;
  int ch = wv * 16 + m;
  f32x4 acc = {0.f, 0.f, 0.f, 0.f};
#pragma unroll
  for (int kb = 0; kb < 3; ++kb){
    int aoff = (kb * 16 + m) * 40 + q * 8;
    s16x8 a_hi = *(const s16x8*)&cA_hi[aoff];
    s16x8 a_lo = *(const s16x8*)&cA_lo[aoff];
    long boff = (((long)(kb * 4 + q)) * 64 + ch) * 8;
    s16x8 b_hi = *(const s16x8*)&WcoB_hi[boff];
    s16x8 b_lo = *(const s16x8*)&WcoB_lo[boff];
    acc = __builtin_amdgcn_mfma_f32_16x16x32_bf16(a_hi, b_hi, acc, 0, 0, 0);
    acc = __builtin_amdgcn_mfma_f32_16x16x32_bf16(a_hi, b_lo, acc, 0, 0, 0);
    acc = __builtin_amdgcn_mfma_f32_16x16x32_bf16(a_lo, b_hi, acc, 0, 0, 0);
  }
#pragma unroll
  for (int reg = 0; reg < 4; ++reg){
    int row = (lane >> 4) * 4 + reg;
    int g = base + row;
    int b = g / NN, n = g - b * NN;
    hB_write(hB_hi, hB_lo, b, n, ch, acc[reg]);
  }
}

// ---------------- masked-softmax GAT: block-local es-max, 2 barriers ----------------
__global__ void __launch_bounds__(256) k_gat(
    const float* __restrict__ ed, const float* __restrict__ es,
    const float* __restrict__ wd_ws, int wd_idx, const u64* __restrict__ adjQ,
    const bf16* __restrict__ distTb,
    const short* __restrict__ hB_hi, const short* __restrict__ hB_lo,
    float* __restrict__ reps){
  __shared__ short pA[32 * 544] __attribute__((aligned(16)));
  __shared__ float redz[TI][4];
  __shared__ float esred[4];
  int t = threadIdx.x;
  int wv = t >> 6, lane = t & 63;
  int b = blockIdx.y;
  int i0 = blockIdx.x * TI;
  float wd = wd_ws[wd_idx];
  int iw = i0 >> 6, sb = i0 & 63;
  int j0 = t * 4;

  const u64* aq = adjQ + ((long)b * 16 + iw) * 1024 + j0;
  u64x2 wA = *(const u64x2*)&aq[0];
  u64x2 wB = *(const u64x2*)&aq[2];
  unsigned wsh[4] = { (unsigned)(wA[0] >> sb), (unsigned)(wA[1] >> sb),
                      (unsigned)(wB[0] >> sb), (unsigned)(wB[1] >> sb) };
  float4 es4 = *(const float4*)&es[(long)b * NN + j0];
  float esv[4] = {es4.x, es4.y, es4.z, es4.w};
  float esm = -1e30f;
#pragma unroll
  for (int c = 0; c < 4; ++c)
    esm = fmaxf(esm, (j0 + c < NN) ? esv[c] : -1e30f);
  esm = wave_bmax(esm);
  if (lane == 0) esred[wv] = esm;

  float ed_i[TI]; float edm = -1e30f;
#pragma unroll
  for (int ti = 0; ti < TI; ++ti){
    int i = i0 + ti;
    float ev = ed[(long)b * NN + ((i < NN) ? i : (NN - 1))];
    ed_i[ti] = ev;
    edm = fmaxf(edm, (i < NN) ? ev : -1e30f);
  }
  __syncthreads();
  float M = fmaxf(fmaxf(esred[0], esred[1]), fmaxf(esred[2], esred[3]))
            + edm + fmaxf(wd, 0.f);
  M = fmaxf(M, 0.f);   // uniform upper bound on all scores; softmax exact

  float p[TI][4];
  const bf16* dbase = distTb + j0;
#pragma unroll
  for (int ti = 0; ti < TI; ++ti){
    int i = i0 + ti;
    int ic = (i < NN) ? i : (NN - 1);
    u16x4 d4 = *(const u16x4*)&dbase[(long)ic * DSTRIDE];
    float edti = ed_i[ti];
#pragma unroll
    for (int c = 0; c < 4; ++c){
      float d = __uint_as_float((unsigned)d4[c] << 16);
      float v = edti + esv[c] + wd * d;
      v = fmaxf(v, 0.2f * v);                 // leaky_relu
      bool edge = (wsh[c] >> ti) & 1u;
      float e = edge ? v : -1e30f;
      p[ti][c] = __expf(e - M);
    }
  }

  int kbw = 8 * wv + (lane >> 3);
  int qw = (lane >> 1) & 3;
  int u0 = 4 * (lane & 1);
  int wbase = kbw * 544 + qw * 136 + u0;
#pragma unroll
  for (int ti = 0; ti < TI; ++ti){
    float zs = p[ti][0] + p[ti][1] + p[ti][2] + p[ti][3];
    zs = wave_bsum(zs);
    if (lane == 0) redz[ti][wv] = zs;
    s16x4 s4 = { f2bs(p[ti][0]), f2bs(p[ti][1]), f2bs(p[ti][2]), f2bs(p[ti][3]) };
    *(s16x4*)&pA[wbase + ti * 8] = s4;
  }
  __syncthreads();

  int q = lane >> 4, m = lane & 15;
  int abase = q * 136 + m * 8;
  int ch = wv * 16 + m;
  const short* bh = hB_hi + (long)b * 65536 + ((long)q * 64 + ch) * 8;
  const short* bl = hB_lo + (long)b * 65536 + ((long)q * 64 + ch) * 8;
  f32x4 acc = {0.f, 0.f, 0.f, 0.f};
#pragma unroll
  for (int kb = 0; kb < 32; ++kb){
    s16x8 a   = *(const s16x8*)&pA[kb * 544 + abase];
    s16x8 bhi = *(const s16x8*)&bh[(long)kb * 2048];
    s16x8 blo = *(const s16x8*)&bl[(long)kb * 2048];
    acc = __builtin_amdgcn_mfma_f32_16x16x32_bf16(a, bhi, acc, 0, 0, 0);
    acc = __builtin_amdgcn_mfma_f32_16x16x32_bf16(a, blo, acc, 0, 0, 0);
  }
#pragma unroll
  for (int reg = 0; reg < 4; ++reg){
    int ti = (lane >> 4) * 4 + reg;
    float z = redz[ti][0] + redz[ti][1] + redz[ti][2] + redz[ti][3];
    float zi = (z > 0.f) ? 1.f / z : 0.f;
    float v = acc[reg] * zi;
    v = (v > 0.f) ? v : expm1f(v);
    int ch2 = wv * 16 + (lane & 15);
    if (i0 + ti < NN)
      reps[((long)b * NN + i0 + ti) * COMD + ch2] = v;
  }
}

// ---------------- x_p = sag@Wp + bp via MFMA; f32 fused scores ----------------
template<bool F32>
__device__ __forceinline__ void xp_body(
    const int* time_idx, const int* op_idx, const void* vf, const void* time_tab,
    const void* cs_tab, const void* tp_tab, const float* comp, const float* coop,
    const short* __restrict__ WpB_hi, const short* __restrict__ WpB_lo,
    const float* __restrict__ wv_ws, const void* bp,
    float* x_p, float* scf, float* scd){
  __shared__ float sagF[16][148] __attribute__((aligned(16)));
  __shared__ short sagA_hi[5 * 16 * 40] __attribute__((aligned(16)));
  __shared__ short sagA_lo[5 * 16 * 40] __attribute__((aligned(16)));
  int t = threadIdx.x;
  int wv = t >> 6, lane = t & 63;
  int base = blockIdx.x * 16;

  for (int idx = t; idx < 16 * 147; idx += 256){
    int nl = idx / 147, f = idx - nl * 147;
    int g = base + nl;
    int n = g % NN;
    float v;
    if (f < 4)       v = ldf<F32>(time_tab, time_idx[g] * 4 + f);
    else if (f < 8)  v = ldf<F32>(cs_tab, n * 4 + (f - 4));
    else if (f < 10) v = ldf<F32>(tp_tab, op_idx[g] * 2 + (f - 8));
    else if (f < 19) v = ldf<F32>(vf, (long)g * 9 + (f - 10));
    else if (f < 83) v = comp[(long)g * COMD + (f - 19)];
    else             v = coop[(long)g * COMD + (f - 83)];
    sagF[nl][f] = v;
  }
  __syncthreads();

  for (int idx = t; idx < 16 * 160; idx += 256){
    int m = idx / 160, k = idx - m * 160;
    float v = (k < 147) ? sagF[m][k] : 0.f;
    int kb = k >> 5, q = (k >> 3) & 3, u = k & 7;
    short hi, lo; split_bf(v, hi, lo);
    int off = (kb * 16 + m) * 40 + q * 8 + u;
    sagA_hi[off] = hi; sagA_lo[off] = lo;
  }
  {
    int node = t >> 4, sub = t & 15;
    float ad = 0.f, af = 0.f;
    for (int f = sub; f < 147; f += 16){
      float s = sagF[node][f];
      ad += s * wv_ws[f];
      af += s * wv_ws[160 + f];
    }
#pragma unroll
    for (int o = 8; o > 0; o >>= 1){
      ad += __shfl_xor(ad, o, 64);
      af += __shfl_xor(af, o, 64);
    }
    if (sub == 0){
      scd[base + node] = ad + wv_ws[320];
      scf[base + node] = af + wv_ws[321];
    }
  }
  __syncthreads();

  int Ag = lane >> 4, Am = lane & 15;
  f32x4 acc[4] = {{0,0,0,0},{0,0,0,0},{0,0,0,0},{0,0,0,0}};
#pragma unroll
  for (int kb = 0; kb < 5; ++kb){
    int aoff = (kb * 16 + Am) * 40 + Ag * 8;
    s16x8 a_hi = *(const s16x8*)&sagA_hi[aoff];
    s16x8 a_lo = *(const s16x8*)&sagA_lo[aoff];
#pragma unroll
    for (int ct = 0; ct < 4; ++ct){
      int ch = wv * 64 + ct * 16 + Am;
      long boff = (((long)(kb * 4 + Ag)) * 256 + ch) * 8;
      s16x8 b_hi = *(const s16x8*)&WpB_hi[boff];
      s16x8 b_lo = *(const s16x8*)&WpB_lo[boff];
      acc[ct] = __builtin_amdgcn_mfma_f32_16x16x32_bf16(a_hi, b_hi, acc[ct], 0, 0, 0);
      acc[ct] = __builtin_amdgcn_mfma_f32_16x16x32_bf16(a_hi, b_lo, acc[ct], 0, 0, 0);
      acc[ct] = __builtin_amdgcn_mfma_f32_16x16x32_bf16(a_lo, b_hi, acc[ct], 0, 0, 0);
    }
  }
#pragma unroll
  for (int ct = 0; ct < 4; ++ct){
    int ch = wv * 64 + ct * 16 + (lane & 15);
    float bb = ldf<F32>(bp, ch);
#pragma unroll
    for (int reg = 0; reg < 4; ++reg){
      int row = (lane >> 4) * 4 + reg;
      x_p[(long)(base + row) * HIDD + ch] = acc[ct][reg] + bb;
    }
  }
}
__global__ void __launch_bounds__(256) k_xp(
    const int* flags, const int* time_idx, const int* op_idx, const void* vf,
    const void* time_tab, const void* cs_tab, const void* tp_tab,
    const float* comp, const float* coop,
    const short* WpB_hi, const short* WpB_lo, const float* wv_ws, const void* bp,
    float* x_p, float* scf, float* scd){
  if (flags[0]) xp_body<true >(time_idx, op_idx, vf, time_tab, cs_tab, tp_tab, comp, coop, WpB_hi, WpB_lo, wv_ws, bp, x_p, scf, scd);
  else          xp_body<false>(time_idx, op_idx, vf, time_tab, cs_tab, tp_tab, comp, coop, WpB_hi, WpB_lo, wv_ws, bp, x_p, scf, scd);
}

// ---------------- top-k weights: one wave per (b,pool) ----------------
template<bool BINT>
__device__ __forceinline__ void topk_body(
    const float* scf, const float* scd, const void* mark, float* wls){
  int lane = threadIdx.x;
  int b = blockIdx.x, pool = blockIdx.y;
  const float* sc = (pool == 0) ? scf : scd;
  float v[16]; unsigned key[16];
  float m0 = -INFINITY;
#pragma unroll
  for (int r = 0; r < 16; ++r){
    int n = r * 64 + lane;
    float s = (n < NN) ? sc[b * NN + n] : -INFINITY;
    v[r] = s;
    m0 = fmaxf(m0, s);
  }
  m0 = wave_bmax(m0);
  float m1 = -INFINITY;
#pragma unroll
  for (int r = 0; r < 16; ++r){
    int n = r * 64 + lane;
    bool valid = false;
    if (n < NN){
      bool mk = ldb<BINT>(mark, b * NN + n);
      valid = (pool == 0) ? !mk : mk;
    }
    v[r] = valid ? (v[r] - m0) : -1e8f;
    key[r] = fkey(v[r]);
    if (n < NN) m1 = fmaxf(m1, v[r]);
  }
  m1 = wave_bmax(m1);

  unsigned lo = 0u, hi = 0xFFFFFFFFu;
  while (lo < hi){
    unsigned mid = lo + ((hi - lo) >> 1) + 1u;
    int c = 0;
#pragma unroll
    for (int r = 0; r < 16; ++r) c += (key[r] >= mid) ? 1 : 0;
    c = wave_bsum_i(c);
    if (c >= KSEL) lo = mid; else hi = mid - 1u;
  }

  float p[16];
  float ls = 0.f;
#pragma unroll
  for (int r = 0; r < 16; ++r){
    int n = r * 64 + lane;
    float pp = (n < NN && key[r] >= lo) ? __expf(v[r] - m1) : 0.f;
    p[r] = pp;
    ls += pp;
  }
  ls = wave_bsum(ls);
  float zinv = (ls > 0.f) ? 1.f / ls : 0.f;
  float* w_out = wls + ((long)b * 2 + pool) * 1024;
#pragma unroll
  for (int r = 0; r < 16; ++r){
    int n = r * 64 + lane;
    if (n < NN) w_out[n] = p[r] * zinv;
  }
}
__global__ void k_topk(const int* flags, const float* scf, const float* scd,
                       const void* mark, float* wls){
  if (flags[1]) topk_body<true >(scf, scd, mark, wls);
  else          topk_body<false>(scf, scd, mark, wls);
}

// ---------------- gated partial sums ----------------
__global__ void __launch_bounds__(256) k_psum(
    const float* __restrict__ wls, const float* __restrict__ x_p,
    float* __restrict__ part){
  __shared__ float wf[ROWS], wdd[ROWS];
  int t = threadIdx.x;
  int b = blockIdx.x, z = blockIdx.y;
  int n0 = z * ROWS;
  int ns = min(ROWS, NN - n0);
  if (t < ns){
    wf[t]  = wls[((long)b * 2 + 0) * 1024 + n0 + t];
    wdd[t] = wls[((long)b * 2 + 1) * 1024 + n0 + t];
  }
  __syncthreads();
  float sf = 0.f, mf = -INFINITY, sd = 0.f, md = -INFINITY;
  const float* xb = x_p + ((long)b * NN + n0) * HIDD + t;
  for (int k = 0; k < ns; ++k){
    float xv = xb[(long)k * HIDD];
    float gf = wf[k] * xv;
    float gd = wdd[k] * xv;
    sf += gf; mf = fmaxf(mf, gf);
    sd += gd; md = fmaxf(md, gd);
  }
  long pb = (((long)b * NSPL + z) * 4) * HIDD + t;
  part[pb + 0 * HIDD] = sf;
  part[pb + 1 * HIDD] = mf;
  part[pb + 2 * HIDD] = sd;
  part[pb + 3 * HIDD] = md;
}

// ---------------- final reduce ----------------
template<bool F32>
__device__ __forceinline__ void pfin_body(const float* part, void* out){
  int t = threadIdx.x;
  int b = blockIdx.x;
  float sf = 0.f, mf = -INFINITY, sd = 0.f, md = -INFINITY;
#pragma unroll
  for (int z = 0; z < NSPL; ++z){
    long pb = (((long)b * NSPL + z) * 4) * HIDD + t;
    sf += part[pb + 0 * HIDD];
    mf = fmaxf(mf, part[pb + 1 * HIDD]);
    sd += part[pb + 2 * HIDD];
    md = fmaxf(md, part[pb + 3 * HIDD]);
  }
  long ob = (long)b * 1024;
  if (F32){
    ((float*)out)[ob + t] = sf;
    ((float*)out)[ob + 256 + t] = mf;
    ((float*)out)[ob + 512 + t] = sd;
    ((float*)out)[ob + 768 + t] = md;
  } else {
    ((bf16*)out)[ob + t] = __float2bfloat16(sf);
    ((bf16*)out)[ob + 256 + t] = __float2bfloat16(mf);
    ((bf16*)out)[ob + 512 + t] = __float2bfloat16(sd);
    ((bf16*)out)[ob + 768 + t] = __float2bfloat16(md);
  }
}
__global__ void k_pfin(const int* flags, const float* part, void* out){
  if (flags[0]) pfin_body<true >(part, out);
  else          pfin_body<false>(part, out);
}

extern "C" void kernel_launch(void* const* d_in, const int* in_sizes, int n_in,
                              void* d_out, int out_size, void* d_ws, size_t ws_size,
                              hipStream_t stream){
  const int*  time_idx = (const int*)d_in[0];
  const int*  op_idx   = (const int*)d_in[1];
  const void* vfeat    = d_in[2];
  const void* dpcs     = d_in[3];
  const void* adj_comp = d_in[4];
  const void* adj_coop = d_in[5];
  const void* dist     = d_in[6];
  const void* time_tab = d_in[7];
  const void* tp_tab   = d_in[8];
  const void* cs_tab   = d_in[9];
  const void* Wc       = d_in[10];
  const void* asrc_c   = d_in[11];
  const void* adst_c   = d_in[12];
  const void* wd_c     = d_in[13];
  const void* Wco      = d_in[14];
  const void* asrc_co  = d_in[15];
  const void* adst_co  = d_in[16];
  const void* wd_co    = d_in[17];
  const void* Wp       = d_in[18];
  const void* bp       = d_in[19];
  const void* vpd      = d_in[20];
  const void* vpf      = d_in[21];

  char* ws = (char*)d_ws;
  size_t o = 0;
  auto alloc = [&](size_t bytes)->char*{
    char* p = ws + o; o = (o + bytes + 255) & ~(size_t)255; return p;
  };
  int*   flags   = (int*)alloc(16);
  float* wd_ws   = (float*)alloc(8);
  bf16*  distTb  = (bf16*)alloc((size_t)NN * DSTRIDE * 2);
  u64*   adjQc   = (u64*)alloc((size_t)NB * 16 * 1024 * 8);
  u64*   adjQo   = (u64*)alloc((size_t)NB * 16 * 1024 * 8);
  float* x_ws    = (float*)alloc((size_t)NB * NN * 15 * 4);
  float* comp    = (float*)alloc((size_t)NB * NN * COMD * 4);
  float* coop    = (float*)alloc((size_t)NB * NN * COMD * 4);
  short* hB_hi   = (short*)alloc((size_t)NB * 65536 * 2);
  short* hB_lo   = (short*)alloc((size_t)NB * 65536 * 2);
  short* WpB_hi  = (short*)alloc((size_t)5 * 4 * 256 * 8 * 2);
  short* WpB_lo  = (short*)alloc((size_t)5 * 4 * 256 * 8 * 2);
  short* WcoB_hi = (short*)alloc((size_t)3 * 4 * 64 * 8 * 2);
  short* WcoB_lo = (short*)alloc((size_t)3 * 4 * 64 * 8 * 2);
  float* wv_ws   = (float*)alloc(322 * 4);
  float* pvco    = (float*)alloc(192 * 4);
  float* ed_c    = (float*)alloc((size_t)NB * NN * 4 + 256);
  float* es_c    = (float*)alloc((size_t)NB * NN * 4 + 256);
  float* ed_o    = (float*)alloc((size_t)NB * NN * 4 + 256);
  float* es_o    = (float*)alloc((size_t)NB * NN * 4 + 256);
  float* scf     = (float*)alloc((size_t)NB * NN * 4);
  float* scd     = (float*)alloc((size_t)NB * NN * 4);
  float* wls     = (float*)alloc((size_t)NB * 2 * 1024 * 4);
  float* part    = (float*)alloc((size_t)NB * NSPL * 4 * HIDD * 4);
  float* x_p     = (float*)alloc((size_t)NB * NN * HIDD * 4);

  k_prep<<<dim3(PB_N), dim3(256), 0, stream>>>(
      dist, adj_comp, adj_coop, wd_c, wd_co, Wp, vpd, vpf, bp,
      Wco, asrc_co, adst_co,
      flags, wd_ws, distTb, adjQc, adjQo, WpB_hi, WpB_lo, wv_ws,
      WcoB_hi, WcoB_lo, pvco);
  k_embed<<<dim3(NB * NN / 4), dim3(256), 0, stream>>>(
      flags, op_idx, vfeat, cs_tab, tp_tab, Wc, asrc_c, adst_c,
      x_ws, hB_hi, hB_lo, ed_c, es_c);
  k_gat<<<dim3((NN + TI - 1) / TI, NB), dim3(256), 0, stream>>>(
      ed_c, es_c, wd_ws, 0, adjQc, distTb, hB_hi, hB_lo, comp);
  k_hco<<<dim3(NB * NN / 16), dim3(256), 0, stream>>>(
      x_ws, comp, WcoB_hi, WcoB_lo, pvco, hB_hi, hB_lo, ed_o, es_o);
  k_gat<<<dim3((NN + TI - 1) / TI, NB), dim3(256), 0, stream>>>(
      ed_o, es_o, wd_ws, 1, adjQo, distTb, hB_hi, hB_lo, coop);
  k_xp<<<dim3(NB * NN / 16), dim3(256), 0, stream>>>(
      flags, time_idx, op_idx, vfeat, time_tab, cs_tab, tp_tab, comp, coop,
      WpB_hi, WpB_lo, wv_ws, bp, x_p, scf, scd);
  k_topk<<<dim3(NB, 2), dim3(64), 0, stream>>>(flags, scf, scd, dpcs, wls);
  k_psum<<<dim3(NB, NSPL), dim3(256), 0, stream>>>(wls, x_p, part);
  k_pfin<<<dim3(NB), dim3(256), 0, stream>>>(flags, part, d_out);
}

// Round 13
// 499.302 us; speedup vs baseline: 1.0348x; 1.0091x over previous
//
#include <hip/hip_runtime.h>
#include <hip/hip_bf16.h>

#define NB 32
#define NN 1000
#define COMD 64
#define HIDD 256
#define KSEL 500
#define TI 16        // dst rows per k_gat block
#define NSPL 32      // n-splits for k_psum
#define ROWS 32      // ceil(NN/NSPL)
#define DSTRIDE 1024 // padded distT row stride

// k_prep role bases (adjq now 8 j's per block -> 4096 blocks per adjacency)
#define PB_DT   0        // 256 dist-transpose tiles
#define PB_AQ1  256      // 4096 adjq comp
#define PB_AQ2  4352     // 4096 adjq coop
#define PB_WP   8448     // 40 blocks x 4 rows = 160 Wp rows
#define PB_WCO  8488     // 24 blocks x 4 rows = 96 Wco rows
#define PB_MISC 8512     // flags, wd, bias dots
#define PB_N    8513

typedef __hip_bfloat16 bf16;
typedef unsigned long long u64;
typedef __attribute__((ext_vector_type(4))) float f32x4;
typedef __attribute__((ext_vector_type(8))) short s16x8;
typedef __attribute__((ext_vector_type(4))) short s16x4;
typedef __attribute__((ext_vector_type(4))) unsigned short u16x4;
typedef __attribute__((ext_vector_type(2))) unsigned long long u64x2;

__device__ __forceinline__ float b2f(bf16 x){ return __bfloat162float(x); }

template<bool F32>
__device__ __forceinline__ float ldf(const void* p, long i){
  return F32 ? ((const float*)p)[i] : b2f(((const bf16*)p)[i]);
}
template<bool BINT>
__device__ __forceinline__ bool ldb(const void* p, long i){
  return BINT ? (((const int*)p)[i] != 0) : (((const unsigned char*)p)[i] != 0);
}

__device__ __forceinline__ float wave_sum(float v){
#pragma unroll
  for (int o = 32; o > 0; o >>= 1) v += __shfl_down(v, o, 64);
  return v;
}
__device__ __forceinline__ float wave_bsum(float v){
#pragma unroll
  for (int o = 32; o > 0; o >>= 1) v += __shfl_xor(v, o, 64);
  return v;
}
__device__ __forceinline__ float wave_bmax(float v){
#pragma unroll
  for (int o = 32; o > 0; o >>= 1) v = fmaxf(v, __shfl_xor(v, o, 64));
  return v;
}
__device__ __forceinline__ int wave_bsum_i(int v){
#pragma unroll
  for (int o = 32; o > 0; o >>= 1) v += __shfl_xor(v, o, 64);
  return v;
}
__device__ __forceinline__ unsigned fkey(float f){
  unsigned u = __float_as_uint(f);
  return (u & 0x80000000u) ? ~u : (u | 0x80000000u);
}
// split fp32 into bf16 hi + bf16 lo with v ≈ hi + lo (residual ~2^-16 rel)
__device__ __forceinline__ void split_bf(float v, short& hi, short& lo){
  unsigned u = __float_as_uint(v);
  float hf = __uint_as_float(u & 0xFFFF0000u);
  hi = (short)(u >> 16);
  float r = v - hf;                 // exact
  lo = (short)(__float_as_uint(r) >> 16);
}
__device__ __forceinline__ short f2bs(float v){
  bf16 h = __float2bfloat16(v);
  short s; __builtin_memcpy(&s, &h, 2); return s;
}
__device__ __forceinline__ void hB_write(short* hB_hi, short* hB_lo,
                                         int b, int n, int ch, float v){
  int kb = n >> 5, g4 = (n >> 3) & 3, u = n & 7;
  long off = ((((long)b * 32 + kb) * 4 + g4) * 64 + ch) * 8 + u;
  short hi, lo; split_bf(v, hi, lo);
  hB_hi[off] = hi; hB_lo[off] = lo;
}
// cheap per-block dtype sniff: 2 loads + 2 ballots
__device__ __forceinline__ void sniff2(const void* dist, const void* adjc,
                                       int lane, int& f32, int& as_int){
  unsigned wdist = ((const unsigned*)dist)[lane];
  unsigned wadj  = ((const unsigned*)adjc)[lane];
  f32 = (__ballot((wdist & 0xFFFFu) >= 0x8000u) != 0ull) ? 1 : 0;
  as_int = (__ballot(wadj > 1u) == 0ull) ? 1 : 0;
}

// ================ k_prep: all input preprocessing in ONE kernel ================
template<bool F32>
__device__ void dist_t_role(const void* dist, bf16* distTb, int rel){
  __shared__ bf16 tile[64][68];
  int t = threadIdx.x;
  int wv = t >> 6, lane = t & 63;
  int it = (rel & 15) * 64, jt = (rel >> 4) * 64;
#pragma unroll
  for (int r = 0; r < 16; ++r){
    int jl = r * 4 + wv;
    int j = jt + jl, i = it + lane;
    float v = (j < NN && i < NN) ? ldf<F32>(dist, (long)j * NN + i) : 0.f;
    tile[jl][lane] = __float2bfloat16(v);
  }
  __syncthreads();
#pragma unroll
  for (int r = 0; r < 16; ++r){
    int il = r * 4 + wv;
    int i = it + il, j = jt + lane;
    if (i < NN) distTb[(long)i * DSTRIDE + j] = tile[lane][il];
  }
}
// adjacency pack v4: contiguous reads + LDS-staged coalesced writes (v3),
// 8 j's per block (4x more blocks) -> latency hidden by TLP: only 2
// load-rounds per wave, 32 blocks/CU queued.
template<bool BINT>
__device__ void adjq_role(const void* adj, u64* adjQ, int rel){
  __shared__ u64 aw[16][9];          // 16 iw x 8 j (+1 pad)
  int t = threadIdx.x;
  int wv = t >> 6, lane = t & 63;
  int j0 = (rel & 127) * 8;
  int b  = rel >> 7;
  int im = lane * 16;
  unsigned vmask = (im >= NN) ? 0u
                 : ((NN - im >= 16) ? 0xFFFFu : ((1u << (NN - im)) - 1u));
#pragma unroll
  for (int r = 0; r < 2; ++r){
    int j = j0 + wv * 2 + r;
    unsigned m = 0;
    if (j < NN){
      if (BINT){
        const char* p = (const char*)adj;
        long base = (((long)b * NN + j) * NN + im) * 4;
        long lim  = (long)NB * NN * NN * 4;
#pragma unroll
        for (int c = 0; c < 4; ++c){
          long off = base + c * 16;
          if (off + 16 <= lim){
            uint4 d = *(const uint4*)(p + off);
            m |= (d.x ? 1u : 0u) << (c * 4 + 0);
            m |= (d.y ? 1u : 0u) << (c * 4 + 1);
            m |= (d.z ? 1u : 0u) << (c * 4 + 2);
            m |= (d.w ? 1u : 0u) << (c * 4 + 3);
          } else {
            const int* ip = (const int*)adj;
            long ib = ((long)b * NN + j) * NN;
#pragma unroll
            for (int k = 0; k < 4; ++k){
              int i = im + c * 4 + k;
              if (i < NN) m |= (ip[ib + i] ? 1u : 0u) << (c * 4 + k);
            }
          }
        }
      } else {
        const char* p = (const char*)adj;
        long base = (long)b * NN * NN + (long)j * NN + im;
        long lim  = (long)NB * NN * NN;
#pragma unroll
        for (int c = 0; c < 2; ++c){
          long off = base + c * 8;
          if (off + 8 <= lim){
            u64 x = *(const u64*)(p + off);
#pragma unroll
            for (int k = 0; k < 8; ++k)
              m |= (((x >> (8 * k)) & 0xFFull) ? 1u : 0u) << (c * 8 + k);
          } else {
#pragma unroll
            for (int k = 0; k < 8; ++k){
              long o2 = off + k;
              if (o2 < lim) m |= (p[o2] ? 1u : 0u) << (c * 8 + k);
            }
          }
        }
      }
      m &= vmask;
    }
    int s = 4 * lane;
    unsigned a0 = (unsigned)__shfl((int)m, (s + 0) & 63, 64);
    unsigned a1 = (unsigned)__shfl((int)m, (s + 1) & 63, 64);
    unsigned a2 = (unsigned)__shfl((int)m, (s + 2) & 63, 64);
    unsigned a3 = (unsigned)__shfl((int)m, (s + 3) & 63, 64);
    if (lane < 16){
      u64 w = (u64)(a0 & 0xFFFFu) | ((u64)(a1 & 0xFFFFu) << 16)
            | ((u64)(a2 & 0xFFFFu) << 32) | ((u64)(a3 & 0xFFFFu) << 48);
      aw[lane][wv * 2 + r] = w;
    }
  }
  __syncthreads();
  // coalesced write-out: 128 words; 16 full 64B lines, one pass
  if (t < 128){
    int iw = t >> 3, jloc = t & 7;
    adjQ[((long)b * 16 + iw) * 1024 + j0 + jloc] = aw[iw][jloc];
  }
}
template<bool F32>
__device__ void wp_role(const void* Wp, const void* vpd, const void* vpf,
                        short* WpB_hi, short* WpB_lo, float* wv_ws, int rel){
  int t = threadIdx.x;
  int g = t >> 6, lane = t & 63;
  int f = rel * 4 + g;               // 0..159
  float wrow[4];
#pragma unroll
  for (int r = 0; r < 4; ++r){
    int ch = r * 64 + lane;
    wrow[r] = (f < 147) ? ldf<F32>(Wp, (long)f * HIDD + ch) : 0.f;
  }
  int kb = f >> 5, q = (f >> 3) & 3, u = f & 7;
#pragma unroll
  for (int r = 0; r < 4; ++r){
    int ch = r * 64 + lane;
    long off = (((long)(kb * 4 + q)) * 256 + ch) * 8 + u;
    short hi, lo; split_bf(wrow[r], hi, lo);
    WpB_hi[off] = hi; WpB_lo[off] = lo;
  }
  float ad = 0.f, af = 0.f;
#pragma unroll
  for (int r = 0; r < 4; ++r){
    int ch = r * 64 + lane;
    ad += wrow[r] * ldf<F32>(vpd, ch);
    af += wrow[r] * ldf<F32>(vpf, ch);
  }
  ad = wave_bsum(ad); af = wave_bsum(af);
  if (lane == 0){ wv_ws[f] = ad; wv_ws[160 + f] = af; }
}
template<bool F32>
__device__ void wco_role(const void* Wco, const void* asrc, const void* adst,
                         short* WcoB_hi, short* WcoB_lo, float* pvco, int rel){
  int t = threadIdx.x;
  int g = t >> 6, lane = t & 63;
  int f = rel * 4 + g;               // 0..95
  float w = (f < 79) ? ldf<F32>(Wco, (long)f * COMD + lane) : 0.f;
  int kb = f >> 5, q = (f >> 3) & 3, u = f & 7;
  long off = (((long)(kb * 4 + q)) * 64 + lane) * 8 + u;
  short hi, lo; split_bf(w, hi, lo);
  WcoB_hi[off] = hi; WcoB_lo[off] = lo;
  float dd = wave_bsum(w * ldf<F32>(adst, lane));
  float ss = wave_bsum(w * ldf<F32>(asrc, lane));
  if (lane == 0){ pvco[f] = dd; pvco[96 + f] = ss; }
}
template<bool F32>
__device__ void misc_role(const void* wdc, const void* wdco,
                          const void* bp, const void* vpd, const void* vpf,
                          int f32, int as_int,
                          int* flags, float* wd_ws, float* wv_ws){
  int t = threadIdx.x;
  if (t >= 64) return;
  int lane = t;
  float ad = 0.f, af = 0.f;
#pragma unroll
  for (int r = 0; r < 4; ++r){
    int ch = r * 64 + lane;
    float bb = ldf<F32>(bp, ch);
    ad += bb * ldf<F32>(vpd, ch);
    af += bb * ldf<F32>(vpf, ch);
  }
  ad = wave_bsum(ad); af = wave_bsum(af);
  if (lane == 0){
    wv_ws[320] = ad; wv_ws[321] = af;
    wd_ws[0] = ldf<F32>(wdc, 0);
    wd_ws[1] = ldf<F32>(wdco, 0);
    flags[0] = f32; flags[1] = as_int;
  }
}
__global__ void __launch_bounds__(256) k_prep(
    const void* dist, const void* adj_comp, const void* adj_coop,
    const void* wdc, const void* wdco,
    const void* Wp, const void* vpd, const void* vpf, const void* bp,
    const void* Wco, const void* asrc_co, const void* adst_co,
    int* flags, float* wd_ws, bf16* distTb, u64* adjQc, u64* adjQo,
    short* WpB_hi, short* WpB_lo, float* wv_ws,
    short* WcoB_hi, short* WcoB_lo, float* pvco){
  int blk = blockIdx.x;
  int f32, as_int;
  sniff2(dist, adj_comp, threadIdx.x & 63, f32, as_int);
  if (blk < PB_AQ1){
    if (f32) dist_t_role<true >(dist, distTb, blk);
    else     dist_t_role<false>(dist, distTb, blk);
  } else if (blk < PB_AQ2){
    if (as_int) adjq_role<true >(adj_comp, adjQc, blk - PB_AQ1);
    else        adjq_role<false>(adj_comp, adjQc, blk - PB_AQ1);
  } else if (blk < PB_WP){
    if (as_int) adjq_role<true >(adj_coop, adjQo, blk - PB_AQ2);
    else        adjq_role<false>(adj_coop, adjQo, blk - PB_AQ2);
  } else if (blk < PB_WCO){
    if (f32) wp_role<true >(Wp, vpd, vpf, WpB_hi, WpB_lo, wv_ws, blk - PB_WP);
    else     wp_role<false>(Wp, vpd, vpf, WpB_hi, WpB_lo, wv_ws, blk - PB_WP);
  } else if (blk < PB_MISC){
    if (f32) wco_role<true >(Wco, asrc_co, adst_co, WcoB_hi, WcoB_lo, pvco, blk - PB_WCO);
    else     wco_role<false>(Wco, asrc_co, adst_co, WcoB_hi, WcoB_lo, pvco, blk - PB_WCO);
  } else {
    if (f32) misc_role<true >(wdc, wdco, bp, vpd, vpf, f32, as_int, flags, wd_ws, wv_ws);
    else     misc_role<false>(wdc, wdco, bp, vpd, vpf, f32, as_int, flags, wd_ws, wv_ws);
  }
}

// ---------------- embedding + h_c (direct to hB planes) + attn scalars ----------------
template<bool F32>
__device__ __forceinline__ void embed_body(
    const int* op_idx, const void* vf, const void* cs_tab, const void* tp_tab,
    const void* Wc, const void* asrc, const void* adst,
    float* x_out, short* hB_hi, short* hB_lo, float* ed_out, float* es_out){
  int t = threadIdx.x;
  int w = t >> 6, lane = t & 63;
  int g = blockIdx.x * 4 + w;
  int b = g / NN, n = g - b * NN;
  int op = op_idx[g];
  float xv = 0.f, hacc = 0.f;
#pragma unroll
  for (int f = 0; f < 15; ++f){
    float x_f;
    if (f < 4)      x_f = ldf<F32>(cs_tab, n * 4 + f);
    else if (f < 6) x_f = ldf<F32>(tp_tab, op * 2 + (f - 4));
    else            x_f = ldf<F32>(vf, (long)g * 9 + (f - 6));
    if (lane == f) xv = x_f;
    hacc += x_f * ldf<F32>(Wc, f * COMD + lane);
  }
  if (lane < 15) x_out[g * 15 + lane] = xv;
  hB_write(hB_hi, hB_lo, b, n, lane, hacc);
  float sd = wave_sum(hacc * ldf<F32>(adst, lane));
  float ss = wave_sum(hacc * ldf<F32>(asrc, lane));
  if (lane == 0){ ed_out[g] = sd; es_out[g] = ss; }
}
__global__ void __launch_bounds__(256) k_embed(
    const int* flags, const int* op_idx, const void* vf, const void* cs_tab,
    const void* tp_tab, const void* Wc, const void* asrc, const void* adst,
    float* x_out, short* hB_hi, short* hB_lo, float* ed_out, float* es_out){
  if (flags[0]) embed_body<true >(op_idx, vf, cs_tab, tp_tab, Wc, asrc, adst, x_out, hB_hi, hB_lo, ed_out, es_out);
  else          embed_body<false>(op_idx, vf, cs_tab, tp_tab, Wc, asrc, adst, x_out, hB_hi, hB_lo, ed_out, es_out);
}

// ---------------- h_co = [x, comp] @ Wco via MFMA; f32 ed/es dots ----------------
__global__ void __launch_bounds__(256) k_hco(
    const float* __restrict__ x_ws, const float* __restrict__ comp,
    const short* __restrict__ WcoB_hi, const short* __restrict__ WcoB_lo,
    const float* __restrict__ pvco,
    short* hB_hi, short* hB_lo, float* ed_out, float* es_out){
  __shared__ float cx[16][80] __attribute__((aligned(16)));
  __shared__ short cA_hi[3 * 16 * 40] __attribute__((aligned(16)));
  __shared__ short cA_lo[3 * 16 * 40] __attribute__((aligned(16)));
  int t = threadIdx.x;
  int wv = t >> 6, lane = t & 63;
  int base = blockIdx.x * 16;
  for (int idx = t; idx < 16 * 79; idx += 256){
    int nl = idx / 79, f = idx - nl * 79;
    int g = base + nl;
    cx[nl][f] = (f < 15) ? x_ws[g * 15 + f] : comp[(long)g * COMD + (f - 15)];
  }
  __syncthreads();
  {
    int node = t >> 4, sub = t & 15;
    float dd = 0.f, ss = 0.f;
    for (int f = sub; f < 79; f += 16){
      float c = cx[node][f];
      dd += c * pvco[f];
      ss += c * pvco[96 + f];
    }
#pragma unroll
    for (int o = 8; o > 0; o >>= 1){
      dd += __shfl_xor(dd, o, 64);
      ss += __shfl_xor(ss, o, 64);
    }
    if (sub == 0){
      int g = base + node;
      ed_out[g] = dd; es_out[g] = ss;
    }
  }
  for (int idx = t; idx < 16 * 96; idx += 256){
    int m = idx / 96, k = idx - m * 96;
    float v = (k < 79) ? cx[m][k] : 0.f;
    int kb = k >> 5, q = (k >> 3) & 3, u = k & 7;
    short hi, lo; split_bf(v, hi, lo);
    int off = (kb * 16 + m) * 40 + q * 8 + u;
    cA_hi[off] = hi; cA_lo[off] = lo;
  }
  __syncthreads();
  int q = lane >> 4, m = lane & 15;
  int ch = wv * 16 + m;
  f32x4 acc = {0.f, 0.f, 0.f, 0.f};
#pragma unroll
  for (int kb = 0; kb < 3; ++kb){
    int aoff = (kb * 16 + m) * 40 + q * 8;
    s16x8 a_hi = *(const s16x8*)&cA_hi[aoff];
    s16x8 a_lo = *(const s16x8*)&cA_lo[aoff];
    long boff = (((long)(kb * 4 + q)) * 64 + ch) * 8;
    s16x8 b_hi = *(const s16x8*)&WcoB_hi[boff];
    s16x8 b_lo = *(const s16x8*)&WcoB_lo[boff];
    acc = __builtin_amdgcn_mfma_f32_16x16x32_bf16(a_hi, b_hi, acc, 0, 0, 0);
    acc = __builtin_amdgcn_mfma_f32_16x16x32_bf16(a_hi, b_lo, acc, 0, 0, 0);
    acc = __builtin_amdgcn_mfma_f32_16x16x32_bf16(a_lo, b_hi, acc, 0, 0, 0);
  }
#pragma unroll
  for (int reg = 0; reg < 4; ++reg){
    int row = (lane >> 4) * 4 + reg;
    int g = base + row;
    int b = g / NN, n = g - b * NN;
    hB_write(hB_hi, hB_lo, b, n, ch, acc[reg]);
  }
}

// ---------------- masked-softmax GAT: block-local es-max, 2 barriers ----------------
__global__ void __launch_bounds__(256) k_gat(
    const float* __restrict__ ed, const float* __restrict__ es,
    const float* __restrict__ wd_ws, int wd_idx, const u64* __restrict__ adjQ,
    const bf16* __restrict__ distTb,
    const short* __restrict__ hB_hi, const short* __restrict__ hB_lo,
    float* __restrict__ reps){
  __shared__ short pA[32 * 544] __attribute__((aligned(16)));
  __shared__ float redz[TI][4];
  __shared__ float esred[4];
  int t = threadIdx.x;
  int wv = t >> 6, lane = t & 63;
  int b = blockIdx.y;
  int i0 = blockIdx.x * TI;
  float wd = wd_ws[wd_idx];
  int iw = i0 >> 6, sb = i0 & 63;
  int j0 = t * 4;

  const u64* aq = adjQ + ((long)b * 16 + iw) * 1024 + j0;
  u64x2 wA = *(const u64x2*)&aq[0];
  u64x2 wB = *(const u64x2*)&aq[2];
  unsigned wsh[4] = { (unsigned)(wA[0] >> sb), (unsigned)(wA[1] >> sb),
                      (unsigned)(wB[0] >> sb), (unsigned)(wB[1] >> sb) };
  float4 es4 = *(const float4*)&es[(long)b * NN + j0];
  float esv[4] = {es4.x, es4.y, es4.z, es4.w};
  float esm = -1e30f;
#pragma unroll
  for (int c = 0; c < 4; ++c)
    esm = fmaxf(esm, (j0 + c < NN) ? esv[c] : -1e30f);
  esm = wave_bmax(esm);
  if (lane == 0) esred[wv] = esm;

  float ed_i[TI]; float edm = -1e30f;
#pragma unroll
  for (int ti = 0; ti < TI; ++ti){
    int i = i0 + ti;
    float ev = ed[(long)b * NN + ((i < NN) ? i : (NN - 1))];
    ed_i[ti] = ev;
    edm = fmaxf(edm, (i < NN) ? ev : -1e30f);
  }
  __syncthreads();
  float M = fmaxf(fmaxf(esred[0], esred[1]), fmaxf(esred[2], esred[3]))
            + edm + fmaxf(wd, 0.f);
  M = fmaxf(M, 0.f);   // uniform upper bound on all scores; softmax exact

  float p[TI][4];
  const bf16* dbase = distTb + j0;
#pragma unroll
  for (int ti = 0; ti < TI; ++ti){
    int i = i0 + ti;
    int ic = (i < NN) ? i : (NN - 1);
    u16x4 d4 = *(const u16x4*)&dbase[(long)ic * DSTRIDE];
    float edti = ed_i[ti];
#pragma unroll
    for (int c = 0; c < 4; ++c){
      float d = __uint_as_float((unsigned)d4[c] << 16);
      float v = edti + esv[c] + wd * d;
      v = fmaxf(v, 0.2f * v);                 // leaky_relu
      bool edge = (wsh[c] >> ti) & 1u;
      float e = edge ? v : -1e30f;
      p[ti][c] = __expf(e - M);
    }
  }

  int kbw = 8 * wv + (lane >> 3);
  int qw = (lane >> 1) & 3;
  int u0 = 4 * (lane & 1);
  int wbase = kbw * 544 + qw * 136 + u0;
#pragma unroll
  for (int ti = 0; ti < TI; ++ti){
    float zs = p[ti][0] + p[ti][1] + p[ti][2] + p[ti][3];
    zs = wave_bsum(zs);
    if (lane == 0) redz[ti][wv] = zs;
    s16x4 s4 = { f2bs(p[ti][0]), f2bs(p[ti][1]), f2bs(p[ti][2]), f2bs(p[ti][3]) };
    *(s16x4*)&pA[wbase + ti * 8] = s4;
  }
  __syncthreads();

  int q = lane >> 4, m = lane & 15;
  int abase = q * 136 + m * 8;
  int ch = wv * 16 + m;
  const short* bh = hB_hi + (long)b * 65536 + ((long)q * 64 + ch) * 8;
  const short* bl = hB_lo + (long)b * 65536 + ((long)q * 64 + ch) * 8;
  f32x4 acc = {0.f, 0.f, 0.f, 0.f};
#pragma unroll
  for (int kb = 0; kb < 32; ++kb){
    s16x8 a   = *(const s16x8*)&pA[kb * 544 + abase];
    s16x8 bhi = *(const s16x8*)&bh[(long)kb * 2048];
    s16x8 blo = *(const s16x8*)&bl[(long)kb * 2048];
    acc = __builtin_amdgcn_mfma_f32_16x16x32_bf16(a, bhi, acc, 0, 0, 0);
    acc = __builtin_amdgcn_mfma_f32_16x16x32_bf16(a, blo, acc, 0, 0, 0);
  }
#pragma unroll
  for (int reg = 0; reg < 4; ++reg){
    int ti = (lane >> 4) * 4 + reg;
    float z = redz[ti][0] + redz[ti][1] + redz[ti][2] + redz[ti][3];
    float zi = (z > 0.f) ? 1.f / z : 0.f;
    float v = acc[reg] * zi;
    v = (v > 0.f) ? v : expm1f(v);
    int ch2 = wv * 16 + (lane & 15);
    if (i0 + ti < NN)
      reps[((long)b * NN + i0 + ti) * COMD + ch2] = v;
  }
}

// ---------------- x_p = sag@Wp + bp via MFMA; f32 fused scores ----------------
template<bool F32>
__device__ __forceinline__ void xp_body(
    const int* time_idx, const int* op_idx, const void* vf, const void* time_tab,
    const void* cs_tab, const void* tp_tab, const float* comp, const float* coop,
    const short* __restrict__ WpB_hi, const short* __restrict__ WpB_lo,
    const float* __restrict__ wv_ws, const void* bp,
    float* x_p, float* scf, float* scd){
  __shared__ float sagF[16][148] __attribute__((aligned(16)));
  __shared__ short sagA_hi[5 * 16 * 40] __attribute__((aligned(16)));
  __shared__ short sagA_lo[5 * 16 * 40] __attribute__((aligned(16)));
  int t = threadIdx.x;
  int wv = t >> 6, lane = t & 63;
  int base = blockIdx.x * 16;

  for (int idx = t; idx < 16 * 147; idx += 256){
    int nl = idx / 147, f = idx - nl * 147;
    int g = base + nl;
    int n = g % NN;
    float v;
    if (f < 4)       v = ldf<F32>(time_tab, time_idx[g] * 4 + f);
    else if (f < 8)  v = ldf<F32>(cs_tab, n * 4 + (f - 4));
    else if (f < 10) v = ldf<F32>(tp_tab, op_idx[g] * 2 + (f - 8));
    else if (f < 19) v = ldf<F32>(vf, (long)g * 9 + (f - 10));
    else if (f < 83) v = comp[(long)g * COMD + (f - 19)];
    else             v = coop[(long)g * COMD + (f - 83)];
    sagF[nl][f] = v;
  }
  __syncthreads();

  for (int idx = t; idx < 16 * 160; idx += 256){
    int m = idx / 160, k = idx - m * 160;
    float v = (k < 147) ? sagF[m][k] : 0.f;
    int kb = k >> 5, q = (k >> 3) & 3, u = k & 7;
    short hi, lo; split_bf(v, hi, lo);
    int off = (kb * 16 + m) * 40 + q * 8 + u;
    sagA_hi[off] = hi; sagA_lo[off] = lo;
  }
  {
    int node = t >> 4, sub = t & 15;
    float ad = 0.f, af = 0.f;
    for (int f = sub; f < 147; f += 16){
      float s = sagF[node][f];
      ad += s * wv_ws[f];
      af += s * wv_ws[160 + f];
    }
#pragma unroll
    for (int o = 8; o > 0; o >>= 1){
      ad += __shfl_xor(ad, o, 64);
      af += __shfl_xor(af, o, 64);
    }
    if (sub == 0){
      scd[base + node] = ad + wv_ws[320];
      scf[base + node] = af + wv_ws[321];
    }
  }
  __syncthreads();

  int Ag = lane >> 4, Am = lane & 15;
  f32x4 acc[4] = {{0,0,0,0},{0,0,0,0},{0,0,0,0},{0,0,0,0}};
#pragma unroll
  for (int kb = 0; kb < 5; ++kb){
    int aoff = (kb * 16 + Am) * 40 + Ag * 8;
    s16x8 a_hi = *(const s16x8*)&sagA_hi[aoff];
    s16x8 a_lo = *(const s16x8*)&sagA_lo[aoff];
#pragma unroll
    for (int ct = 0; ct < 4; ++ct){
      int ch = wv * 64 + ct * 16 + Am;
      long boff = (((long)(kb * 4 + Ag)) * 256 + ch) * 8;
      s16x8 b_hi = *(const s16x8*)&WpB_hi[boff];
      s16x8 b_lo = *(const s16x8*)&WpB_lo[boff];
      acc[ct] = __builtin_amdgcn_mfma_f32_16x16x32_bf16(a_hi, b_hi, acc[ct], 0, 0, 0);
      acc[ct] = __builtin_amdgcn_mfma_f32_16x16x32_bf16(a_hi, b_lo, acc[ct], 0, 0, 0);
      acc[ct] = __builtin_amdgcn_mfma_f32_16x16x32_bf16(a_lo, b_hi, acc[ct], 0, 0, 0);
    }
  }
#pragma unroll
  for (int ct = 0; ct < 4; ++ct){
    int ch = wv * 64 + ct * 16 + (lane & 15);
    float bb = ldf<F32>(bp, ch);
#pragma unroll
    for (int reg = 0; reg < 4; ++reg){
      int row = (lane >> 4) * 4 + reg;
      x_p[(long)(base + row) * HIDD + ch] = acc[ct][reg] + bb;
    }
  }
}
__global__ void __launch_bounds__(256) k_xp(
    const int* flags, const int* time_idx, const int* op_idx, const void* vf,
    const void* time_tab, const void* cs_tab, const void* tp_tab,
    const float* comp, const float* coop,
    const short* WpB_hi, const short* WpB_lo, const float* wv_ws, const void* bp,
    float* x_p, float* scf, float* scd){
  if (flags[0]) xp_body<true >(time_idx, op_idx, vf, time_tab, cs_tab, tp_tab, comp, coop, WpB_hi, WpB_lo, wv_ws, bp, x_p, scf, scd);
  else          xp_body<false>(time_idx, op_idx, vf, time_tab, cs_tab, tp_tab, comp, coop, WpB_hi, WpB_lo, wv_ws, bp, x_p, scf, scd);
}

// ---------------- top-k weights: one wave per (b,pool) ----------------
template<bool BINT>
__device__ __forceinline__ void topk_body(
    const float* scf, const float* scd, const void* mark, float* wls){
  int lane = threadIdx.x;
  int b = blockIdx.x, pool = blockIdx.y;
  const float* sc = (pool == 0) ? scf : scd;
  float v[16]; unsigned key[16];
  float m0 = -INFINITY;
#pragma unroll
  for (int r = 0; r < 16; ++r){
    int n = r * 64 + lane;
    float s = (n < NN) ? sc[b * NN + n] : -INFINITY;
    v[r] = s;
    m0 = fmaxf(m0, s);
  }
  m0 = wave_bmax(m0);
  float m1 = -INFINITY;
#pragma unroll
  for (int r = 0; r < 16; ++r){
    int n = r * 64 + lane;
    bool valid = false;
    if (n < NN){
      bool mk = ldb<BINT>(mark, b * NN + n);
      valid = (pool == 0) ? !mk : mk;
    }
    v[r] = valid ? (v[r] - m0) : -1e8f;
    key[r] = fkey(v[r]);
    if (n < NN) m1 = fmaxf(m1, v[r]);
  }
  m1 = wave_bmax(m1);

  unsigned lo = 0u, hi = 0xFFFFFFFFu;
  while (lo < hi){
    unsigned mid = lo + ((hi - lo) >> 1) + 1u;
    int c = 0;
#pragma unroll
    for (int r = 0; r < 16; ++r) c += (key[r] >= mid) ? 1 : 0;
    c = wave_bsum_i(c);
    if (c >= KSEL) lo = mid; else hi = mid - 1u;
  }

  float p[16];
  float ls = 0.f;
#pragma unroll
  for (int r = 0; r < 16; ++r){
    int n = r * 64 + lane;
    float pp = (n < NN && key[r] >= lo) ? __expf(v[r] - m1) : 0.f;
    p[r] = pp;
    ls += pp;
  }
  ls = wave_bsum(ls);
  float zinv = (ls > 0.f) ? 1.f / ls : 0.f;
  float* w_out = wls + ((long)b * 2 + pool) * 1024;
#pragma unroll
  for (int r = 0; r < 16; ++r){
    int n = r * 64 + lane;
    if (n < NN) w_out[n] = p[r] * zinv;
  }
}
__global__ void k_topk(const int* flags, const float* scf, const float* scd,
                       const void* mark, float* wls){
  if (flags[1]) topk_body<true >(scf, scd, mark, wls);
  else          topk_body<false>(scf, scd, mark, wls);
}

// ---------------- gated partial sums ----------------
__global__ void __launch_bounds__(256) k_psum(
    const float* __restrict__ wls, const float* __restrict__ x_p,
    float* __restrict__ part){
  __shared__ float wf[ROWS], wdd[ROWS];
  int t = threadIdx.x;
  int b = blockIdx.x, z = blockIdx.y;
  int n0 = z * ROWS;
  int ns = min(ROWS, NN - n0);
  if (t < ns){
    wf[t]  = wls[((long)b * 2 + 0) * 1024 + n0 + t];
    wdd[t] = wls[((long)b * 2 + 1) * 1024 + n0 + t];
  }
  __syncthreads();
  float sf = 0.f, mf = -INFINITY, sd = 0.f, md = -INFINITY;
  const float* xb = x_p + ((long)b * NN + n0) * HIDD + t;
  for (int k = 0; k < ns; ++k){
    float xv = xb[(long)k * HIDD];
    float gf = wf[k] * xv;
    float gd = wdd[k] * xv;
    sf += gf; mf = fmaxf(mf, gf);
    sd += gd; md = fmaxf(md, gd);
  }
  long pb = (((long)b * NSPL + z) * 4) * HIDD + t;
  part[pb + 0 * HIDD] = sf;
  part[pb + 1 * HIDD] = mf;
  part[pb + 2 * HIDD] = sd;
  part[pb + 3 * HIDD] = md;
}

// ---------------- final reduce ----------------
template<bool F32>
__device__ __forceinline__ void pfin_body(const float* part, void* out){
  int t = threadIdx.x;
  int b = blockIdx.x;
  float sf = 0.f, mf = -INFINITY, sd = 0.f, md = -INFINITY;
#pragma unroll
  for (int z = 0; z < NSPL; ++z){
    long pb = (((long)b * NSPL + z) * 4) * HIDD + t;
    sf += part[pb + 0 * HIDD];
    mf = fmaxf(mf, part[pb + 1 * HIDD]);
    sd += part[pb + 2 * HIDD];
    md = fmaxf(md, part[pb + 3 * HIDD]);
  }
  long ob = (long)b * 1024;
  if (F32){
    ((float*)out)[ob + t] = sf;
    ((float*)out)[ob + 256 + t] = mf;
    ((float*)out)[ob + 512 + t] = sd;
    ((float*)out)[ob + 768 + t] = md;
  } else {
    ((bf16*)out)[ob + t] = __float2bfloat16(sf);
    ((bf16*)out)[ob + 256 + t] = __float2bfloat16(mf);
    ((bf16*)out)[ob + 512 + t] = __float2bfloat16(sd);
    ((bf16*)out)[ob + 768 + t] = __float2bfloat16(md);
  }
}
__global__ void k_pfin(const int* flags, const float* part, void* out){
  if (flags[0]) pfin_body<true >(part, out);
  else          pfin_body<false>(part, out);
}

extern "C" void kernel_launch(void* const* d_in, const int* in_sizes, int n_in,
                              void* d_out, int out_size, void* d_ws, size_t ws_size,
                              hipStream_t stream){
  const int*  time_idx = (const int*)d_in[0];
  const int*  op_idx   = (const int*)d_in[1];
  const void* vfeat    = d_in[2];
  const void* dpcs     = d_in[3];
  const void* adj_comp = d_in[4];
  const void* adj_coop = d_in[5];
  const void* dist     = d_in[6];
  const void* time_tab = d_in[7];
  const void* tp_tab   = d_in[8];
  const void* cs_tab   = d_in[9];
  const void* Wc       = d_in[10];
  const void* asrc_c   = d_in[11];
  const void* adst_c   = d_in[12];
  const void* wd_c     = d_in[13];
  const void* Wco      = d_in[14];
  const void* asrc_co  = d_in[15];
  const void* adst_co  = d_in[16];
  const void* wd_co    = d_in[17];
  const void* Wp       = d_in[18];
  const void* bp       = d_in[19];
  const void* vpd      = d_in[20];
  const void* vpf      = d_in[21];

  char* ws = (char*)d_ws;
  size_t o = 0;
  auto alloc = [&](size_t bytes)->char*{
    char* p = ws + o; o = (o + bytes + 255) & ~(size_t)255; return p;
  };
  int*   flags   = (int*)alloc(16);
  float* wd_ws   = (float*)alloc(8);
  bf16*  distTb  = (bf16*)alloc((size_t)NN * DSTRIDE * 2);
  u64*   adjQc   = (u64*)alloc((size_t)NB * 16 * 1024 * 8);
  u64*   adjQo   = (u64*)alloc((size_t)NB * 16 * 1024 * 8);
  float* x_ws    = (float*)alloc((size_t)NB * NN * 15 * 4);
  float* comp    = (float*)alloc((size_t)NB * NN * COMD * 4);
  float* coop    = (float*)alloc((size_t)NB * NN * COMD * 4);
  short* hB_hi   = (short*)alloc((size_t)NB * 65536 * 2);
  short* hB_lo   = (short*)alloc((size_t)NB * 65536 * 2);
  short* WpB_hi  = (short*)alloc((size_t)5 * 4 * 256 * 8 * 2);
  short* WpB_lo  = (short*)alloc((size_t)5 * 4 * 256 * 8 * 2);
  short* WcoB_hi = (short*)alloc((size_t)3 * 4 * 64 * 8 * 2);
  short* WcoB_lo = (short*)alloc((size_t)3 * 4 * 64 * 8 * 2);
  float* wv_ws   = (float*)alloc(322 * 4);
  float* pvco    = (float*)alloc(192 * 4);
  float* ed_c    = (float*)alloc((size_t)NB * NN * 4 + 256);
  float* es_c    = (float*)alloc((size_t)NB * NN * 4 + 256);
  float* ed_o    = (float*)alloc((size_t)NB * NN * 4 + 256);
  float* es_o    = (float*)alloc((size_t)NB * NN * 4 + 256);
  float* scf     = (float*)alloc((size_t)NB * NN * 4);
  float* scd     = (float*)alloc((size_t)NB * NN * 4);
  float* wls     = (float*)alloc((size_t)NB * 2 * 1024 * 4);
  float* part    = (float*)alloc((size_t)NB * NSPL * 4 * HIDD * 4);
  float* x_p     = (float*)alloc((size_t)NB * NN * HIDD * 4);

  k_prep<<<dim3(PB_N), dim3(256), 0, stream>>>(
      dist, adj_comp, adj_coop, wd_c, wd_co, Wp, vpd, vpf, bp,
      Wco, asrc_co, adst_co,
      flags, wd_ws, distTb, adjQc, adjQo, WpB_hi, WpB_lo, wv_ws,
      WcoB_hi, WcoB_lo, pvco);
  k_embed<<<dim3(NB * NN / 4), dim3(256), 0, stream>>>(
      flags, op_idx, vfeat, cs_tab, tp_tab, Wc, asrc_c, adst_c,
      x_ws, hB_hi, hB_lo, ed_c, es_c);
  k_gat<<<dim3((NN + TI - 1) / TI, NB), dim3(256), 0, stream>>>(
      ed_c, es_c, wd_ws, 0, adjQc, distTb, hB_hi, hB_lo, comp);
  k_hco<<<dim3(NB * NN / 16), dim3(256), 0, stream>>>(
      x_ws, comp, WcoB_hi, WcoB_lo, pvco, hB_hi, hB_lo, ed_o, es_o);
  k_gat<<<dim3((NN + TI - 1) / TI, NB), dim3(256), 0, stream>>>(
      ed_o, es_o, wd_ws, 1, adjQo, distTb, hB_hi, hB_lo, coop);
  k_xp<<<dim3(NB * NN / 16), dim3(256), 0, stream>>>(
      flags, time_idx, op_idx, vfeat, time_tab, cs_tab, tp_tab, comp, coop,
      WpB_hi, WpB_lo, wv_ws, bp, x_p, scf, scd);
  k_topk<<<dim3(NB, 2), dim3(64), 0, stream>>>(flags, scf, scd, dpcs, wls);
  k_psum<<<dim3(NB, NSPL), dim3(256), 0, stream>>>(wls, x_p, part);
  k_pfin<<<dim3(NB), dim3(256), 0, stream>>>(flags, part, d_out);
}

// Round 14
// 498.485 us; speedup vs baseline: 1.0365x; 1.0016x over previous
//
#include <hip/hip_runtime.h>
#include <hip/hip_bf16.h>

#define NB 32
#define NN 1000
#define COMD 64
#define HIDD 256
#define KSEL 500
#define TI 16        // dst rows per k_gat block
#define NSPL 32      // n-splits for k_psum
#define ROWS 32      // ceil(NN/NSPL)
#define DSTRIDE 1024 // padded distT row stride

// k_prep role bases (adjq: 32 j's per block -> 1024 blocks per adjacency)
#define PB_DT   0        // 256 dist-transpose tiles
#define PB_AQ1  256      // 1024 adjq comp
#define PB_AQ2  1280     // 1024 adjq coop
#define PB_WP   2304     // 40 blocks x 4 rows = 160 Wp rows
#define PB_WCO  2344     // 24 blocks x 4 rows = 96 Wco rows
#define PB_MISC 2368     // flags, wd, bias dots
#define PB_N    2369

typedef __hip_bfloat16 bf16;
typedef unsigned long long u64;
typedef __attribute__((ext_vector_type(4))) float f32x4;
typedef __attribute__((ext_vector_type(8))) short s16x8;
typedef __attribute__((ext_vector_type(4))) short s16x4;
typedef __attribute__((ext_vector_type(4))) unsigned short u16x4;
typedef __attribute__((ext_vector_type(2))) unsigned long long u64x2;

__device__ __forceinline__ float b2f(bf16 x){ return __bfloat162float(x); }

template<bool F32>
__device__ __forceinline__ float ldf(const void* p, long i){
  return F32 ? ((const float*)p)[i] : b2f(((const bf16*)p)[i]);
}
template<bool BINT>
__device__ __forceinline__ bool ldb(const void* p, long i){
  return BINT ? (((const int*)p)[i] != 0) : (((const unsigned char*)p)[i] != 0);
}

__device__ __forceinline__ float wave_sum(float v){
#pragma unroll
  for (int o = 32; o > 0; o >>= 1) v += __shfl_down(v, o, 64);
  return v;
}
__device__ __forceinline__ float wave_bsum(float v){
#pragma unroll
  for (int o = 32; o > 0; o >>= 1) v += __shfl_xor(v, o, 64);
  return v;
}
__device__ __forceinline__ float wave_bmax(float v){
#pragma unroll
  for (int o = 32; o > 0; o >>= 1) v = fmaxf(v, __shfl_xor(v, o, 64));
  return v;
}
__device__ __forceinline__ int wave_bsum_i(int v){
#pragma unroll
  for (int o = 32; o > 0; o >>= 1) v += __shfl_xor(v, o, 64);
  return v;
}
__device__ __forceinline__ unsigned fkey(float f){
  unsigned u = __float_as_uint(f);
  return (u & 0x80000000u) ? ~u : (u | 0x80000000u);
}
// split fp32 into bf16 hi + bf16 lo with v ≈ hi + lo (residual ~2^-16 rel)
__device__ __forceinline__ void split_bf(float v, short& hi, short& lo){
  unsigned u = __float_as_uint(v);
  float hf = __uint_as_float(u & 0xFFFF0000u);
  hi = (short)(u >> 16);
  float r = v - hf;                 // exact
  lo = (short)(__float_as_uint(r) >> 16);
}
__device__ __forceinline__ short f2bs(float v){
  bf16 h = __float2bfloat16(v);
  short s; __builtin_memcpy(&s, &h, 2); return s;
}
__device__ __forceinline__ void hB_write(short* hB_hi, short* hB_lo,
                                         int b, int n, int ch, float v){
  int kb = n >> 5, g4 = (n >> 3) & 3, u = n & 7;
  long off = ((((long)b * 32 + kb) * 4 + g4) * 64 + ch) * 8 + u;
  short hi, lo; split_bf(v, hi, lo);
  hB_hi[off] = hi; hB_lo[off] = lo;
}
// cheap per-block dtype sniff: 2 loads + 2 ballots
__device__ __forceinline__ void sniff2(const void* dist, const void* adjc,
                                       int lane, int& f32, int& as_int){
  unsigned wdist = ((const unsigned*)dist)[lane];
  unsigned wadj  = ((const unsigned*)adjc)[lane];
  f32 = (__ballot((wdist & 0xFFFFu) >= 0x8000u) != 0ull) ? 1 : 0;
  as_int = (__ballot(wadj > 1u) == 0ull) ? 1 : 0;
}

// ================ k_prep: all input preprocessing in ONE kernel ================
template<bool F32>
__device__ void dist_t_role(const void* dist, bf16* distTb, int rel){
  __shared__ bf16 tile[64][68];
  int t = threadIdx.x;
  int wv = t >> 6, lane = t & 63;
  int it = (rel & 15) * 64, jt = (rel >> 4) * 64;
#pragma unroll
  for (int r = 0; r < 16; ++r){
    int jl = r * 4 + wv;
    int j = jt + jl, i = it + lane;
    float v = (j < NN && i < NN) ? ldf<F32>(dist, (long)j * NN + i) : 0.f;
    tile[jl][lane] = __float2bfloat16(v);
  }
  __syncthreads();
#pragma unroll
  for (int r = 0; r < 16; ++r){
    int il = r * 4 + wv;
    int i = it + il, j = jt + lane;
    if (i < NN) distTb[(long)i * DSTRIDE + j] = tile[lane][il];
  }
}
// adjacency pack v5: interleaved fully-coalesced reads + ballot assembly.
// Lane L loads the 4-i chunk c*64+L (consecutive lanes -> consecutive
// addresses, 1KB/256B per wave insn, 4 insns per row = minimum). Words are
// stored in PERMUTED bit order: bit p holds i-offset il with
// p = 16*(il&3) + (il>>2); k_gat extracts with matching constant shifts.
template<bool BINT>
__device__ void adjq_role(const void* adj, u64* adjQ, int rel){
  __shared__ u64 aw[16][33];         // +1 pad
  int t = threadIdx.x;
  int wv = t >> 6, lane = t & 63;
  int j0 = (rel & 31) * 32;
  int b  = rel >> 5;
  for (int r = 0; r < 8; ++r){
    int j = j0 + wv * 8 + r;
    int jc = (j < NN) ? j : (NN - 1);
    long row = ((long)b * NN + jc) * NN;     // element index of row start
#pragma unroll
    for (int c = 0; c < 4; ++c){
      int chunk = c * 64 + lane;
      bool okc = chunk < 250;                // 250 chunks of 4 i's per row
      bool p0, p1, p2, p3;
      if (BINT){
        uint4 d = {0u, 0u, 0u, 0u};
        if (okc) d = *(const uint4*)((const int*)adj + row + (long)chunk * 4);
        p0 = d.x != 0u; p1 = d.y != 0u; p2 = d.z != 0u; p3 = d.w != 0u;
      } else {
        unsigned d = 0u;
        if (okc) d = *(const unsigned*)((const unsigned char*)adj + row + (long)chunk * 4);
        p0 = (d & 0xFFu) != 0u;       p1 = (d & 0xFF00u) != 0u;
        p2 = (d & 0xFF0000u) != 0u;   p3 = (d & 0xFF000000u) != 0u;
      }
      u64 bal0 = __ballot(p0), bal1 = __ballot(p1);
      u64 bal2 = __ballot(p2), bal3 = __ballot(p3);
      if (lane < 4){
        u64 w = 0;
        if (j < NN){
          int sh = 16 * lane;                // sub-word w' = lane
          w = ((bal0 >> sh) & 0xFFFFull)
            | (((bal1 >> sh) & 0xFFFFull) << 16)
            | (((bal2 >> sh) & 0xFFFFull) << 32)
            | (((bal3 >> sh) & 0xFFFFull) << 48);
        }
        aw[c * 4 + lane][wv * 8 + r] = w;    // iw = 4c + w'
      }
    }
  }
  __syncthreads();
  // coalesced write-out: 512 words; threads 0..31 cover one iw-row (256 B)
#pragma unroll
  for (int rr = 0; rr < 2; ++rr){
    int w2 = t + rr * 256;
    int iw = w2 >> 5, jloc = w2 & 31;
    adjQ[((long)b * 16 + iw) * 1024 + j0 + jloc] = aw[iw][jloc];
  }
}
template<bool F32>
__device__ void wp_role(const void* Wp, const void* vpd, const void* vpf,
                        short* WpB_hi, short* WpB_lo, float* wv_ws, int rel){
  int t = threadIdx.x;
  int g = t >> 6, lane = t & 63;
  int f = rel * 4 + g;               // 0..159
  float wrow[4];
#pragma unroll
  for (int r = 0; r < 4; ++r){
    int ch = r * 64 + lane;
    wrow[r] = (f < 147) ? ldf<F32>(Wp, (long)f * HIDD + ch) : 0.f;
  }
  int kb = f >> 5, q = (f >> 3) & 3, u = f & 7;
#pragma unroll
  for (int r = 0; r < 4; ++r){
    int ch = r * 64 + lane;
    long off = (((long)(kb * 4 + q)) * 256 + ch) * 8 + u;
    short hi, lo; split_bf(wrow[r], hi, lo);
    WpB_hi[off] = hi; WpB_lo[off] = lo;
  }
  float ad = 0.f, af = 0.f;
#pragma unroll
  for (int r = 0; r < 4; ++r){
    int ch = r * 64 + lane;
    ad += wrow[r] * ldf<F32>(vpd, ch);
    af += wrow[r] * ldf<F32>(vpf, ch);
  }
  ad = wave_bsum(ad); af = wave_bsum(af);
  if (lane == 0){ wv_ws[f] = ad; wv_ws[160 + f] = af; }
}
template<bool F32>
__device__ void wco_role(const void* Wco, const void* asrc, const void* adst,
                         short* WcoB_hi, short* WcoB_lo, float* pvco, int rel){
  int t = threadIdx.x;
  int g = t >> 6, lane = t & 63;
  int f = rel * 4 + g;               // 0..95
  float w = (f < 79) ? ldf<F32>(Wco, (long)f * COMD + lane) : 0.f;
  int kb = f >> 5, q = (f >> 3) & 3, u = f & 7;
  long off = (((long)(kb * 4 + q)) * 64 + lane) * 8 + u;
  short hi, lo; split_bf(w, hi, lo);
  WcoB_hi[off] = hi; WcoB_lo[off] = lo;
  float dd = wave_bsum(w * ldf<F32>(adst, lane));
  float ss = wave_bsum(w * ldf<F32>(asrc, lane));
  if (lane == 0){ pvco[f] = dd; pvco[96 + f] = ss; }
}
template<bool F32>
__device__ void misc_role(const void* wdc, const void* wdco,
                          const void* bp, const void* vpd, const void* vpf,
                          int f32, int as_int,
                          int* flags, float* wd_ws, float* wv_ws){
  int t = threadIdx.x;
  if (t >= 64) return;
  int lane = t;
  float ad = 0.f, af = 0.f;
#pragma unroll
  for (int r = 0; r < 4; ++r){
    int ch = r * 64 + lane;
    float bb = ldf<F32>(bp, ch);
    ad += bb * ldf<F32>(vpd, ch);
    af += bb * ldf<F32>(vpf, ch);
  }
  ad = wave_bsum(ad); af = wave_bsum(af);
  if (lane == 0){
    wv_ws[320] = ad; wv_ws[321] = af;
    wd_ws[0] = ldf<F32>(wdc, 0);
    wd_ws[1] = ldf<F32>(wdco, 0);
    flags[0] = f32; flags[1] = as_int;
  }
}
__global__ void __launch_bounds__(256) k_prep(
    const void* dist, const void* adj_comp, const void* adj_coop,
    const void* wdc, const void* wdco,
    const void* Wp, const void* vpd, const void* vpf, const void* bp,
    const void* Wco, const void* asrc_co, const void* adst_co,
    int* flags, float* wd_ws, bf16* distTb, u64* adjQc, u64* adjQo,
    short* WpB_hi, short* WpB_lo, float* wv_ws,
    short* WcoB_hi, short* WcoB_lo, float* pvco){
  int blk = blockIdx.x;
  int f32, as_int;
  sniff2(dist, adj_comp, threadIdx.x & 63, f32, as_int);
  if (blk < PB_AQ1){
    if (f32) dist_t_role<true >(dist, distTb, blk);
    else     dist_t_role<false>(dist, distTb, blk);
  } else if (blk < PB_AQ2){
    if (as_int) adjq_role<true >(adj_comp, adjQc, blk - PB_AQ1);
    else        adjq_role<false>(adj_comp, adjQc, blk - PB_AQ1);
  } else if (blk < PB_WP){
    if (as_int) adjq_role<true >(adj_coop, adjQo, blk - PB_AQ2);
    else        adjq_role<false>(adj_coop, adjQo, blk - PB_AQ2);
  } else if (blk < PB_WCO){
    if (f32) wp_role<true >(Wp, vpd, vpf, WpB_hi, WpB_lo, wv_ws, blk - PB_WP);
    else     wp_role<false>(Wp, vpd, vpf, WpB_hi, WpB_lo, wv_ws, blk - PB_WP);
  } else if (blk < PB_MISC){
    if (f32) wco_role<true >(Wco, asrc_co, adst_co, WcoB_hi, WcoB_lo, pvco, blk - PB_WCO);
    else     wco_role<false>(Wco, asrc_co, adst_co, WcoB_hi, WcoB_lo, pvco, blk - PB_WCO);
  } else {
    if (f32) misc_role<true >(wdc, wdco, bp, vpd, vpf, f32, as_int, flags, wd_ws, wv_ws);
    else     misc_role<false>(wdc, wdco, bp, vpd, vpf, f32, as_int, flags, wd_ws, wv_ws);
  }
}

// ---------------- embedding + h_c (direct to hB planes) + attn scalars ----------------
template<bool F32>
__device__ __forceinline__ void embed_body(
    const int* op_idx, const void* vf, const void* cs_tab, const void* tp_tab,
    const void* Wc, const void* asrc, const void* adst,
    float* x_out, short* hB_hi, short* hB_lo, float* ed_out, float* es_out){
  int t = threadIdx.x;
  int w = t >> 6, lane = t & 63;
  int g = blockIdx.x * 4 + w;
  int b = g / NN, n = g - b * NN;
  int op = op_idx[g];
  float xv = 0.f, hacc = 0.f;
#pragma unroll
  for (int f = 0; f < 15; ++f){
    float x_f;
    if (f < 4)      x_f = ldf<F32>(cs_tab, n * 4 + f);
    else if (f < 6) x_f = ldf<F32>(tp_tab, op * 2 + (f - 4));
    else            x_f = ldf<F32>(vf, (long)g * 9 + (f - 6));
    if (lane == f) xv = x_f;
    hacc += x_f * ldf<F32>(Wc, f * COMD + lane);
  }
  if (lane < 15) x_out[g * 15 + lane] = xv;
  hB_write(hB_hi, hB_lo, b, n, lane, hacc);
  float sd = wave_sum(hacc * ldf<F32>(adst, lane));
  float ss = wave_sum(hacc * ldf<F32>(asrc, lane));
  if (lane == 0){ ed_out[g] = sd; es_out[g] = ss; }
}
__global__ void __launch_bounds__(256) k_embed(
    const int* flags, const int* op_idx, const void* vf, const void* cs_tab,
    const void* tp_tab, const void* Wc, const void* asrc, const void* adst,
    float* x_out, short* hB_hi, short* hB_lo, float* ed_out, float* es_out){
  if (flags[0]) embed_body<true >(op_idx, vf, cs_tab, tp_tab, Wc, asrc, adst, x_out, hB_hi, hB_lo, ed_out, es_out);
  else          embed_body<false>(op_idx, vf, cs_tab, tp_tab, Wc, asrc, adst, x_out, hB_hi, hB_lo, ed_out, es_out);
}

// ---------------- h_co = [x, comp] @ Wco via MFMA; f32 ed/es dots ----------------
__global__ void __launch_bounds__(256) k_hco(
    const float* __restrict__ x_ws, const float* __restrict__ comp,
    const short* __restrict__ WcoB_hi, const short* __restrict__ WcoB_lo,
    const float* __restrict__ pvco,
    short* hB_hi, short* hB_lo, float* ed_out, float* es_out){
  __shared__ float cx[16][80] __attribute__((aligned(16)));
  __shared__ short cA_hi[3 * 16 * 40] __attribute__((aligned(16)));
  __shared__ short cA_lo[3 * 16 * 40] __attribute__((aligned(16)));
  int t = threadIdx.x;
  int wv = t >> 6, lane = t & 63;
  int base = blockIdx.x * 16;
  for (int idx = t; idx < 16 * 79; idx += 256){
    int nl = idx / 79, f = idx - nl * 79;
    int g = base + nl;
    cx[nl][f] = (f < 15) ? x_ws[g * 15 + f] : comp[(long)g * COMD + (f - 15)];
  }
  __syncthreads();
  {
    int node = t >> 4, sub = t & 15;
    float dd = 0.f, ss = 0.f;
    for (int f = sub; f < 79; f += 16){
      float c = cx[node][f];
      dd += c * pvco[f];
      ss += c * pvco[96 + f];
    }
#pragma unroll
    for (int o = 8; o > 0; o >>= 1){
      dd += __shfl_xor(dd, o, 64);
      ss += __shfl_xor(ss, o, 64);
    }
    if (sub == 0){
      int g = base + node;
      ed_out[g] = dd; es_out[g] = ss;
    }
  }
  for (int idx = t; idx < 16 * 96; idx += 256){
    int m = idx / 96, k = idx - m * 96;
    float v = (k < 79) ? cx[m][k] : 0.f;
    int kb = k >> 5, q = (k >> 3) & 3, u = k & 7;
    short hi, lo; split_bf(v, hi, lo);
    int off = (kb * 16 + m) * 40 + q * 8 + u;
    cA_hi[off] = hi; cA_lo[off] = lo;
  }
  __syncthreads();
  int q = lane >> 4, m = lane & 15;
  int ch = wv * 16 + m;
  f32x4 acc = {0.f, 0.f, 0.f, 0.f};
#pragma unroll
  for (int kb = 0; kb < 3; ++kb){
    int aoff = (kb * 16 + m) * 40 + q * 8;
    s16x8 a_hi = *(const s16x8*)&cA_hi[aoff];
    s16x8 a_lo = *(const s16x8*)&cA_lo[aoff];
    long boff = (((long)(kb * 4 + q)) * 64 + ch) * 8;
    s16x8 b_hi = *(const s16x8*)&WcoB_hi[boff];
    s16x8 b_lo = *(const s16x8*)&WcoB_lo[boff];
    acc = __builtin_amdgcn_mfma_f32_16x16x32_bf16(a_hi, b_hi, acc, 0, 0, 0);
    acc = __builtin_amdgcn_mfma_f32_16x16x32_bf16(a_hi, b_lo, acc, 0, 0, 0);
    acc = __builtin_amdgcn_mfma_f32_16x16x32_bf16(a_lo, b_hi, acc, 0, 0, 0);
  }
#pragma unroll
  for (int reg = 0; reg < 4; ++reg){
    int row = (lane >> 4) * 4 + reg;
    int g = base + row;
    int b = g / NN, n = g - b * NN;
    hB_write(hB_hi, hB_lo, b, n, ch, acc[reg]);
  }
}

// ---------------- masked-softmax GAT: permuted-bit adjQ extraction ----------------
__global__ void __launch_bounds__(256) k_gat(
    const float* __restrict__ ed, const float* __restrict__ es,
    const float* __restrict__ wd_ws, int wd_idx, const u64* __restrict__ adjQ,
    const bf16* __restrict__ distTb,
    const short* __restrict__ hB_hi, const short* __restrict__ hB_lo,
    float* __restrict__ reps){
  __shared__ short pA[32 * 544] __attribute__((aligned(16)));
  __shared__ float redz[TI][4];
  __shared__ float esred[4];
  int t = threadIdx.x;
  int wv = t >> 6, lane = t & 63;
  int b = blockIdx.y;
  int i0 = blockIdx.x * TI;
  float wd = wd_ws[wd_idx];
  int iw = i0 >> 6;
  int sb2 = (i0 & 63) >> 2;       // permuted-order uniform shift
  int j0 = t * 4;

  const u64* aq = adjQ + ((long)b * 16 + iw) * 1024 + j0;
  u64x2 wA = *(const u64x2*)&aq[0];
  u64x2 wB = *(const u64x2*)&aq[2];
  u64 wsh[4] = { wA[0] >> sb2, wA[1] >> sb2, wB[0] >> sb2, wB[1] >> sb2 };
  float4 es4 = *(const float4*)&es[(long)b * NN + j0];
  float esv[4] = {es4.x, es4.y, es4.z, es4.w};
  float esm = -1e30f;
#pragma unroll
  for (int c = 0; c < 4; ++c)
    esm = fmaxf(esm, (j0 + c < NN) ? esv[c] : -1e30f);
  esm = wave_bmax(esm);
  if (lane == 0) esred[wv] = esm;

  float ed_i[TI]; float edm = -1e30f;
#pragma unroll
  for (int ti = 0; ti < TI; ++ti){
    int i = i0 + ti;
    float ev = ed[(long)b * NN + ((i < NN) ? i : (NN - 1))];
    ed_i[ti] = ev;
    edm = fmaxf(edm, (i < NN) ? ev : -1e30f);
  }
  __syncthreads();
  float M = fmaxf(fmaxf(esred[0], esred[1]), fmaxf(esred[2], esred[3]))
            + edm + fmaxf(wd, 0.f);
  M = fmaxf(M, 0.f);   // uniform upper bound on all scores; softmax exact

  float p[TI][4];
  const bf16* dbase = distTb + j0;
#pragma unroll
  for (int ti = 0; ti < TI; ++ti){
    int i = i0 + ti;
    int ic = (i < NN) ? i : (NN - 1);
    u16x4 d4 = *(const u16x4*)&dbase[(long)ic * DSTRIDE];
    float edti = ed_i[ti];
    int psh = 16 * (ti & 3) + (ti >> 2);      // permuted bit position
#pragma unroll
    for (int c = 0; c < 4; ++c){
      float d = __uint_as_float((unsigned)d4[c] << 16);
      float v = edti + esv[c] + wd * d;
      v = fmaxf(v, 0.2f * v);                 // leaky_relu
      bool edge = (wsh[c] >> psh) & 1ull;
      float e = edge ? v : -1e30f;
      p[ti][c] = __expf(e - M);
    }
  }

  int kbw = 8 * wv + (lane >> 3);
  int qw = (lane >> 1) & 3;
  int u0 = 4 * (lane & 1);
  int wbase = kbw * 544 + qw * 136 + u0;
#pragma unroll
  for (int ti = 0; ti < TI; ++ti){
    float zs = p[ti][0] + p[ti][1] + p[ti][2] + p[ti][3];
    zs = wave_bsum(zs);
    if (lane == 0) redz[ti][wv] = zs;
    s16x4 s4 = { f2bs(p[ti][0]), f2bs(p[ti][1]), f2bs(p[ti][2]), f2bs(p[ti][3]) };
    *(s16x4*)&pA[wbase + ti * 8] = s4;
  }
  __syncthreads();

  int q = lane >> 4, m = lane & 15;
  int abase = q * 136 + m * 8;
  int ch = wv * 16 + m;
  const short* bh = hB_hi + (long)b * 65536 + ((long)q * 64 + ch) * 8;
  const short* bl = hB_lo + (long)b * 65536 + ((long)q * 64 + ch) * 8;
  f32x4 acc = {0.f, 0.f, 0.f, 0.f};
#pragma unroll
  for (int kb = 0; kb < 32; ++kb){
    s16x8 a   = *(const s16x8*)&pA[kb * 544 + abase];
    s16x8 bhi = *(const s16x8*)&bh[(long)kb * 2048];
    s16x8 blo = *(const s16x8*)&bl[(long)kb * 2048];
    acc = __builtin_amdgcn_mfma_f32_16x16x32_bf16(a, bhi, acc, 0, 0, 0);
    acc = __builtin_amdgcn_mfma_f32_16x16x32_bf16(a, blo, acc, 0, 0, 0);
  }
#pragma unroll
  for (int reg = 0; reg < 4; ++reg){
    int ti = (lane >> 4) * 4 + reg;
    float z = redz[ti][0] + redz[ti][1] + redz[ti][2] + redz[ti][3];
    float zi = (z > 0.f) ? 1.f / z : 0.f;
    float v = acc[reg] * zi;
    v = (v > 0.f) ? v : expm1f(v);
    int ch2 = wv * 16 + (lane & 15);
    if (i0 + ti < NN)
      reps[((long)b * NN + i0 + ti) * COMD + ch2] = v;
  }
}

// ---------------- x_p = sag@Wp + bp via MFMA; f32 fused scores ----------------
template<bool F32>
__device__ __forceinline__ void xp_body(
    const int* time_idx, const int* op_idx, const void* vf, const void* time_tab,
    const void* cs_tab, const void* tp_tab, const float* comp, const float* coop,
    const short* __restrict__ WpB_hi, const short* __restrict__ WpB_lo,
    const float* __restrict__ wv_ws, const void* bp,
    float* x_p, float* scf, float* scd){
  __shared__ float sagF[16][148] __attribute__((aligned(16)));
  __shared__ short sagA_hi[5 * 16 * 40] __attribute__((aligned(16)));
  __shared__ short sagA_lo[5 * 16 * 40] __attribute__((aligned(16)));
  int t = threadIdx.x;
  int wv = t >> 6, lane = t & 63;
  int base = blockIdx.x * 16;

  for (int idx = t; idx < 16 * 147; idx += 256){
    int nl = idx / 147, f = idx - nl * 147;
    int g = base + nl;
    int n = g % NN;
    float v;
    if (f < 4)       v = ldf<F32>(time_tab, time_idx[g] * 4 + f);
    else if (f < 8)  v = ldf<F32>(cs_tab, n * 4 + (f - 4));
    else if (f < 10) v = ldf<F32>(tp_tab, op_idx[g] * 2 + (f - 8));
    else if (f < 19) v = ldf<F32>(vf, (long)g * 9 + (f - 10));
    else if (f < 83) v = comp[(long)g * COMD + (f - 19)];
    else             v = coop[(long)g * COMD + (f - 83)];
    sagF[nl][f] = v;
  }
  __syncthreads();

  for (int idx = t; idx < 16 * 160; idx += 256){
    int m = idx / 160, k = idx - m * 160;
    float v = (k < 147) ? sagF[m][k] : 0.f;
    int kb = k >> 5, q = (k >> 3) & 3, u = k & 7;
    short hi, lo; split_bf(v, hi, lo);
    int off = (kb * 16 + m) * 40 + q * 8 + u;
    sagA_hi[off] = hi; sagA_lo[off] = lo;
  }
  {
    int node = t >> 4, sub = t & 15;
    float ad = 0.f, af = 0.f;
    for (int f = sub; f < 147; f += 16){
      float s = sagF[node][f];
      ad += s * wv_ws[f];
      af += s * wv_ws[160 + f];
    }
#pragma unroll
    for (int o = 8; o > 0; o >>= 1){
      ad += __shfl_xor(ad, o, 64);
      af += __shfl_xor(af, o, 64);
    }
    if (sub == 0){
      scd[base + node] = ad + wv_ws[320];
      scf[base + node] = af + wv_ws[321];
    }
  }
  __syncthreads();

  int Ag = lane >> 4, Am = lane & 15;
  f32x4 acc[4] = {{0,0,0,0},{0,0,0,0},{0,0,0,0},{0,0,0,0}};
#pragma unroll
  for (int kb = 0; kb < 5; ++kb){
    int aoff = (kb * 16 + Am) * 40 + Ag * 8;
    s16x8 a_hi = *(const s16x8*)&sagA_hi[aoff];
    s16x8 a_lo = *(const s16x8*)&sagA_lo[aoff];
#pragma unroll
    for (int ct = 0; ct < 4; ++ct){
      int ch = wv * 64 + ct * 16 + Am;
      long boff = (((long)(kb * 4 + Ag)) * 256 + ch) * 8;
      s16x8 b_hi = *(const s16x8*)&WpB_hi[boff];
      s16x8 b_lo = *(const s16x8*)&WpB_lo[boff];
      acc[ct] = __builtin_amdgcn_mfma_f32_16x16x32_bf16(a_hi, b_hi, acc[ct], 0, 0, 0);
      acc[ct] = __builtin_amdgcn_mfma_f32_16x16x32_bf16(a_hi, b_lo, acc[ct], 0, 0, 0);
      acc[ct] = __builtin_amdgcn_mfma_f32_16x16x32_bf16(a_lo, b_hi, acc[ct], 0, 0, 0);
    }
  }
#pragma unroll
  for (int ct = 0; ct < 4; ++ct){
    int ch = wv * 64 + ct * 16 + (lane & 15);
    float bb = ldf<F32>(bp, ch);
#pragma unroll
    for (int reg = 0; reg < 4; ++reg){
      int row = (lane >> 4) * 4 + reg;
      x_p[(long)(base + row) * HIDD + ch] = acc[ct][reg] + bb;
    }
  }
}
__global__ void __launch_bounds__(256) k_xp(
    const int* flags, const int* time_idx, const int* op_idx, const void* vf,
    const void* time_tab, const void* cs_tab, const void* tp_tab,
    const float* comp, const float* coop,
    const short* WpB_hi, const short* WpB_lo, const float* wv_ws, const void* bp,
    float* x_p, float* scf, float* scd){
  if (flags[0]) xp_body<true >(time_idx, op_idx, vf, time_tab, cs_tab, tp_tab, comp, coop, WpB_hi, WpB_lo, wv_ws, bp, x_p, scf, scd);
  else          xp_body<false>(time_idx, op_idx, vf, time_tab, cs_tab, tp_tab, comp, coop, WpB_hi, WpB_lo, wv_ws, bp, x_p, scf, scd);
}

// ---------------- top-k weights: one wave per (b,pool) ----------------
template<bool BINT>
__device__ __forceinline__ void topk_body(
    const float* scf, const float* scd, const void* mark, float* wls){
  int lane = threadIdx.x;
  int b = blockIdx.x, pool = blockIdx.y;
  const float* sc = (pool == 0) ? scf : scd;
  float v[16]; unsigned key[16];
  float m0 = -INFINITY;
#pragma unroll
  for (int r = 0; r < 16; ++r){
    int n = r * 64 + lane;
    float s = (n < NN) ? sc[b * NN + n] : -INFINITY;
    v[r] = s;
    m0 = fmaxf(m0, s);
  }
  m0 = wave_bmax(m0);
  float m1 = -INFINITY;
#pragma unroll
  for (int r = 0; r < 16; ++r){
    int n = r * 64 + lane;
    bool valid = false;
    if (n < NN){
      bool mk = ldb<BINT>(mark, b * NN + n);
      valid = (pool == 0) ? !mk : mk;
    }
    v[r] = valid ? (v[r] - m0) : -1e8f;
    key[r] = fkey(v[r]);
    if (n < NN) m1 = fmaxf(m1, v[r]);
  }
  m1 = wave_bmax(m1);

  unsigned lo = 0u, hi = 0xFFFFFFFFu;
  while (lo < hi){
    unsigned mid = lo + ((hi - lo) >> 1) + 1u;
    int c = 0;
#pragma unroll
    for (int r = 0; r < 16; ++r) c += (key[r] >= mid) ? 1 : 0;
    c = wave_bsum_i(c);
    if (c >= KSEL) lo = mid; else hi = mid - 1u;
  }

  float p[16];
  float ls = 0.f;
#pragma unroll
  for (int r = 0; r < 16; ++r){
    int n = r * 64 + lane;
    float pp = (n < NN && key[r] >= lo) ? __expf(v[r] - m1) : 0.f;
    p[r] = pp;
    ls += pp;
  }
  ls = wave_bsum(ls);
  float zinv = (ls > 0.f) ? 1.f / ls : 0.f;
  float* w_out = wls + ((long)b * 2 + pool) * 1024;
#pragma unroll
  for (int r = 0; r < 16; ++r){
    int n = r * 64 + lane;
    if (n < NN) w_out[n] = p[r] * zinv;
  }
}
__global__ void k_topk(const int* flags, const float* scf, const float* scd,
                       const void* mark, float* wls){
  if (flags[1]) topk_body<true >(scf, scd, mark, wls);
  else          topk_body<false>(scf, scd, mark, wls);
}

// ---------------- gated partial sums ----------------
__global__ void __launch_bounds__(256) k_psum(
    const float* __restrict__ wls, const float* __restrict__ x_p,
    float* __restrict__ part){
  __shared__ float wf[ROWS], wdd[ROWS];
  int t = threadIdx.x;
  int b = blockIdx.x, z = blockIdx.y;
  int n0 = z * ROWS;
  int ns = min(ROWS, NN - n0);
  if (t < ns){
    wf[t]  = wls[((long)b * 2 + 0) * 1024 + n0 + t];
    wdd[t] = wls[((long)b * 2 + 1) * 1024 + n0 + t];
  }
  __syncthreads();
  float sf = 0.f, mf = -INFINITY, sd = 0.f, md = -INFINITY;
  const float* xb = x_p + ((long)b * NN + n0) * HIDD + t;
  for (int k = 0; k < ns; ++k){
    float xv = xb[(long)k * HIDD];
    float gf = wf[k] * xv;
    float gd = wdd[k] * xv;
    sf += gf; mf = fmaxf(mf, gf);
    sd += gd; md = fmaxf(md, gd);
  }
  long pb = (((long)b * NSPL + z) * 4) * HIDD + t;
  part[pb + 0 * HIDD] = sf;
  part[pb + 1 * HIDD] = mf;
  part[pb + 2 * HIDD] = sd;
  part[pb + 3 * HIDD] = md;
}

// ---------------- final reduce ----------------
template<bool F32>
__device__ __forceinline__ void pfin_body(const float* part, void* out){
  int t = threadIdx.x;
  int b = blockIdx.x;
  float sf = 0.f, mf = -INFINITY, sd = 0.f, md = -INFINITY;
#pragma unroll
  for (int z = 0; z < NSPL; ++z){
    long pb = (((long)b * NSPL + z) * 4) * HIDD + t;
    sf += part[pb + 0 * HIDD];
    mf = fmaxf(mf, part[pb + 1 * HIDD]);
    sd += part[pb + 2 * HIDD];
    md = fmaxf(md, part[pb + 3 * HIDD]);
  }
  long ob = (long)b * 1024;
  if (F32){
    ((float*)out)[ob + t] = sf;
    ((float*)out)[ob + 256 + t] = mf;
    ((float*)out)[ob + 512 + t] = sd;
    ((float*)out)[ob + 768 + t] = md;
  } else {
    ((bf16*)out)[ob + t] = __float2bfloat16(sf);
    ((bf16*)out)[ob + 256 + t] = __float2bfloat16(mf);
    ((bf16*)out)[ob + 512 + t] = __float2bfloat16(sd);
    ((bf16*)out)[ob + 768 + t] = __float2bfloat16(md);
  }
}
__global__ void k_pfin(const int* flags, const float* part, void* out){
  if (flags[0]) pfin_body<true >(part, out);
  else          pfin_body<false>(part, out);
}

extern "C" void kernel_launch(void* const* d_in, const int* in_sizes, int n_in,
                              void* d_out, int out_size, void* d_ws, size_t ws_size,
                              hipStream_t stream){
  const int*  time_idx = (const int*)d_in[0];
  const int*  op_idx   = (const int*)d_in[1];
  const void* vfeat    = d_in[2];
  const void* dpcs     = d_in[3];
  const void* adj_comp = d_in[4];
  const void* adj_coop = d_in[5];
  const void* dist     = d_in[6];
  const void* time_tab = d_in[7];
  const void* tp_tab   = d_in[8];
  const void* cs_tab   = d_in[9];
  const void* Wc       = d_in[10];
  const void* asrc_c   = d_in[11];
  const void* adst_c   = d_in[12];
  const void* wd_c     = d_in[13];
  const void* Wco      = d_in[14];
  const void* asrc_co  = d_in[15];
  const void* adst_co  = d_in[16];
  const void* wd_co    = d_in[17];
  const void* Wp       = d_in[18];
  const void* bp       = d_in[19];
  const void* vpd      = d_in[20];
  const void* vpf      = d_in[21];

  char* ws = (char*)d_ws;
  size_t o = 0;
  auto alloc = [&](size_t bytes)->char*{
    char* p = ws + o; o = (o + bytes + 255) & ~(size_t)255; return p;
  };
  int*   flags   = (int*)alloc(16);
  float* wd_ws   = (float*)alloc(8);
  bf16*  distTb  = (bf16*)alloc((size_t)NN * DSTRIDE * 2);
  u64*   adjQc   = (u64*)alloc((size_t)NB * 16 * 1024 * 8);
  u64*   adjQo   = (u64*)alloc((size_t)NB * 16 * 1024 * 8);
  float* x_ws    = (float*)alloc((size_t)NB * NN * 15 * 4);
  float* comp    = (float*)alloc((size_t)NB * NN * COMD * 4);
  float* coop    = (float*)alloc((size_t)NB * NN * COMD * 4);
  short* hB_hi   = (short*)alloc((size_t)NB * 65536 * 2);
  short* hB_lo   = (short*)alloc((size_t)NB * 65536 * 2);
  short* WpB_hi  = (short*)alloc((size_t)5 * 4 * 256 * 8 * 2);
  short* WpB_lo  = (short*)alloc((size_t)5 * 4 * 256 * 8 * 2);
  short* WcoB_hi = (short*)alloc((size_t)3 * 4 * 64 * 8 * 2);
  short* WcoB_lo = (short*)alloc((size_t)3 * 4 * 64 * 8 * 2);
  float* wv_ws   = (float*)alloc(322 * 4);
  float* pvco    = (float*)alloc(192 * 4);
  float* ed_c    = (float*)alloc((size_t)NB * NN * 4 + 256);
  float* es_c    = (float*)alloc((size_t)NB * NN * 4 + 256);
  float* ed_o    = (float*)alloc((size_t)NB * NN * 4 + 256);
  float* es_o    = (float*)alloc((size_t)NB * NN * 4 + 256);
  float* scf     = (float*)alloc((size_t)NB * NN * 4);
  float* scd     = (float*)alloc((size_t)NB * NN * 4);
  float* wls     = (float*)alloc((size_t)NB * 2 * 1024 * 4);
  float* part    = (float*)alloc((size_t)NB * NSPL * 4 * HIDD * 4);
  float* x_p     = (float*)alloc((size_t)NB * NN * HIDD * 4);

  k_prep<<<dim3(PB_N), dim3(256), 0, stream>>>(
      dist, adj_comp, adj_coop, wd_c, wd_co, Wp, vpd, vpf, bp,
      Wco, asrc_co, adst_co,
      flags, wd_ws, distTb, adjQc, adjQo, WpB_hi, WpB_lo, wv_ws,
      WcoB_hi, WcoB_lo, pvco);
  k_embed<<<dim3(NB * NN / 4), dim3(256), 0, stream>>>(
      flags, op_idx, vfeat, cs_tab, tp_tab, Wc, asrc_c, adst_c,
      x_ws, hB_hi, hB_lo, ed_c, es_c);
  k_gat<<<dim3((NN + TI - 1) / TI, NB), dim3(256), 0, stream>>>(
      ed_c, es_c, wd_ws, 0, adjQc, distTb, hB_hi, hB_lo, comp);
  k_hco<<<dim3(NB * NN / 16), dim3(256), 0, stream>>>(
      x_ws, comp, WcoB_hi, WcoB_lo, pvco, hB_hi, hB_lo, ed_o, es_o);
  k_gat<<<dim3((NN + TI - 1) / TI, NB), dim3(256), 0, stream>>>(
      ed_o, es_o, wd_ws, 1, adjQo, distTb, hB_hi, hB_lo, coop);
  k_xp<<<dim3(NB * NN / 16), dim3(256), 0, stream>>>(
      flags, time_idx, op_idx, vfeat, time_tab, cs_tab, tp_tab, comp, coop,
      WpB_hi, WpB_lo, wv_ws, bp, x_p, scf, scd);
  k_topk<<<dim3(NB, 2), dim3(64), 0, stream>>>(flags, scf, scd, dpcs, wls);
  k_psum<<<dim3(NB, NSPL), dim3(256), 0, stream>>>(wls, x_p, part);
  k_pfin<<<dim3(NB), dim3(256), 0, stream>>>(flags, part, d_out);
}